// Round 6
// baseline (386.061 us; speedup 1.0000x reference)
//
#include <hip/hip_runtime.h>
#include <hip/hip_bf16.h>
#include <math.h>

// Problem constants (SchNet reference)
#define NATOMS 16384
#define NMOL   512
#define APM    32
#define GDIM   50
#define KTAB   4096   // filter lookup-table knots over d in [0,6] (nearest-knot)

#define STRH 132      // s_h row stride (floats), 528B
#define STRA 136      // s_agg / s_t row stride (ushorts), 272B

typedef __attribute__((ext_vector_type(8))) short   short8;   // 8 bf16 (A/B frag)
typedef __attribute__((ext_vector_type(4))) float   floatx4;  // C/D frag

// fast shifted softplus: log(1+exp(x)) - log2, via HW v_exp_f32/v_log_f32
__device__ __forceinline__ float ssp(float x) {
    float e = __expf(-fabsf(x));
    return fmaxf(x, 0.0f) + __logf(1.0f + e) - 0.69314718055994531f;
}

__device__ __forceinline__ unsigned short f2bf(float x) {
    union { float f; unsigned int u; } v; v.f = x;
    unsigned int lsb = (v.u >> 16) & 1u;
    v.u += 0x7fffu + lsb;
    return (unsigned short)(v.u >> 16);
}

__device__ __forceinline__ unsigned int pk2bf(float a, float b) {
    __hip_bfloat162 h = __float22bfloat162_rn(make_float2(a, b));
    unsigned int u;
    __builtin_memcpy(&u, &h, 4);
    return u;
}

// ---------------------------------------------------------------------------
// MEGA-SETUP (single dispatch, 3 block regions):
//  [0,NMOL):       dense pair-knot table koG[mol][dst][src] (byte offsets,
//                  sentinel = zero-row) computed straight from positions
//                  (edge set == {d<=6, i!=j}; boundary edges have weight ~0).
//                  Blocks 0..2 also zero the sentinel table rows.
//  [NMOL,+WB):     weights fp32 -> bf16 B-frag transpose (9x128x128 + out1)
//  [NMOL+WB,+192): filter table, 64 tiles x 3 layers, plain bf16 rows:
//                  T[l][k][f] = ((ssp(ea(d_k)@w1+b1)@w2)+b2)*cut(d_k)
//  Each layer has KTAB+1 rows; row KTAB is all-zero (dense-gather sentinel).
// ---------------------------------------------------------------------------
#define KW1 72
#define KW2 136
#define NTILE (KTAB / 64)   // 64 tiles per layer

__global__ __launch_bounds__(256) void mega_setup_kernel(
    const float* __restrict__ pos,
    unsigned* __restrict__ koG,
    const float* __restrict__ cf1, const float* __restrict__ cf2,
    const float* __restrict__ lin, const float* __restrict__ out1,
    unsigned short* __restrict__ Wtall,
    const float* __restrict__ w1_, const float* __restrict__ b1_,
    const float* __restrict__ w2_, const float* __restrict__ b2_,
    unsigned short* __restrict__ Tt)
{
    const int WB = (9 * 16384 + 64 * 128 + 255) / 256;
    const int b = blockIdx.x;
    const int tid = threadIdx.x;

    __shared__ float sp[96];

    if (b < NMOL) {
        // ---- dense koG for molecule b ----
        if (tid < 96) sp[tid] = pos[b * 96 + tid];
        if (b < 3 && tid < 128)
            Tt[(size_t)b * (KTAB + 1) * 128 + (size_t)KTAB * 128 + tid] = 0;  // zero row
        __syncthreads();
        #pragma unroll
        for (int c4 = 0; c4 < 4; c4++) {
            int c = c4 * 256 + tid;
            int i = c >> 5, j = c & 31;          // dst i, src j
            float dx = sp[3 * i]     - sp[3 * j];
            float dy = sp[3 * i + 1] - sp[3 * j + 1];
            float dz = sp[3 * i + 2] - sp[3 * j + 2];
            float d  = sqrtf(dx * dx + dy * dy + dz * dz);
            unsigned off = (unsigned)(KTAB << 8);      // sentinel: zero row
            if (i != j && d <= 6.0f) {
                float u = d * (float)(KTAB - 1) / 6.0f;
                int k = min((int)(u + 0.5f), KTAB - 1);
                off = (unsigned)(k << 8);
            }
            koG[((size_t)b << 10) + c] = off;
        }
        return;
    }
    if (b < NMOL + WB) {
        int idx = (b - NMOL) * 256 + tid;
        if (idx < 9 * 16384) {
            int wi = idx >> 14, rem = idx & 16383;
            int n = rem >> 7, k = rem & 127;
            int l = wi / 3, which = wi % 3;
            const float* src = (which == 0) ? cf1 : (which == 1) ? cf2 : lin;
            Wtall[idx] = f2bf(src[(size_t)l * 16384 + k * 128 + n]);
        } else if (idx < 9 * 16384 + 64 * 128) {
            int q = idx - 9 * 16384;
            int n = q >> 7, k = q & 127;
            Wtall[idx] = f2bf(out1[k * 64 + n]);
        }
        return;
    }

    // ---------------- table region: tt = (layer, tile) ----------------
    __shared__ unsigned short s_bufA[128 * KW2];   // w2T
    __shared__ unsigned short s_bufB[128 * KW1];   // w1T, then s_t (alias)

    const int tt = b - NMOL - WB;
    const int l  = tt / NTILE;
    const int bx = tt % NTILE;
    const float* w1 = w1_ + (size_t)l * GDIM * 128;
    const float* b1 = b1_ + (size_t)l * 128;
    const float* w2 = w2_ + (size_t)l * 128 * 128;
    const float* b2 = b2_ + (size_t)l * 128;
    unsigned short* Tg = Tt + (size_t)l * (KTAB + 1) * 128;

    unsigned short* s_w1T = s_bufB;                // [128][KW1]
    unsigned short* s_w2T = s_bufA;                // [128][KW2]
    unsigned short* s_t   = s_bufB;                // [64][KW2] (after barrier)

    for (int i = tid; i < GDIM * 128; i += 256) {
        int g = i >> 7, f = i & 127;
        s_w1T[f * KW1 + g] = f2bf(w1[i]);
    }
    for (int i = tid; i < (64 - GDIM) * 128; i += 256) {
        int g = GDIM + (i >> 7), f = i & 127;
        s_w1T[f * KW1 + g] = 0;
    }
    for (int i = tid; i < 128 * 128; i += 256) {
        int k = i >> 7, n = i & 127;
        s_w2T[n * KW2 + k] = f2bf(w2[i]);
    }

    const int lane = tid & 63;
    const int w    = tid >> 6;
    const int l15  = lane & 15;
    const int quad = lane >> 4;

    float b1v[8], b2v[8];
    #pragma unroll
    for (int nt = 0; nt < 8; nt++) {
        b1v[nt] = b1[nt * 16 + l15];
        b2v[nt] = b2[nt * 16 + l15];
    }
    __syncthreads();

    const float hstep = 6.0f / (float)(KTAB - 1);
    const float step  = 6.0f / 49.0f;
    const float coeff = -0.5f / (step * step);
    const float pioc  = 3.14159265358979323846f / 6.0f;
    const int k0 = bx * 64;
    const float dm = (float)(k0 + w * 16 + l15) * hstep;

    floatx4 acc1[8];
    #pragma unroll
    for (int nt = 0; nt < 8; nt++) acc1[nt] = (floatx4){0.f, 0.f, 0.f, 0.f};
    #pragma unroll
    for (int ks = 0; ks < 2; ks++) {
        unsigned int ap[4];
        #pragma unroll
        for (int jj = 0; jj < 4; jj++) {
            int g0 = ks * 32 + quad * 8 + 2 * jj;
            float d0 = dm - (float)g0 * step;
            float d1 = dm - (float)(g0 + 1) * step;
            float v0 = (g0 < GDIM)     ? __expf(coeff * d0 * d0) : 0.0f;
            float v1 = (g0 + 1 < GDIM) ? __expf(coeff * d1 * d1) : 0.0f;
            ap[jj] = pk2bf(v0, v1);
        }
        short8 af;
        __builtin_memcpy(&af, ap, 16);
        #pragma unroll
        for (int nt = 0; nt < 8; nt++) {
            short8 bfg = *(const short8*)&s_w1T[(nt * 16 + l15) * KW1 + ks * 32 + quad * 8];
            acc1[nt] = __builtin_amdgcn_mfma_f32_16x16x32_bf16(af, bfg, acc1[nt], 0, 0, 0);
        }
    }
    __syncthreads();   // all waves done reading s_w1T; s_t may alias it

    #pragma unroll
    for (int nt = 0; nt < 8; nt++) {
        #pragma unroll
        for (int r = 0; r < 4; r++) {
            int row = w * 16 + quad * 4 + r;
            s_t[row * KW2 + nt * 16 + l15] = f2bf(ssp(acc1[nt][r] + b1v[nt]));
        }
    }
    // no barrier: wave reads only rows it wrote

    floatx4 acc2[8];
    #pragma unroll
    for (int nt = 0; nt < 8; nt++) acc2[nt] = (floatx4){0.f, 0.f, 0.f, 0.f};
    #pragma unroll
    for (int ks = 0; ks < 4; ks++) {
        short8 af = *(const short8*)&s_t[(w * 16 + l15) * KW2 + ks * 32 + quad * 8];
        #pragma unroll
        for (int nt = 0; nt < 8; nt++) {
            short8 bfg = *(const short8*)&s_w2T[(nt * 16 + l15) * KW2 + ks * 32 + quad * 8];
            acc2[nt] = __builtin_amdgcn_mfma_f32_16x16x32_bf16(af, bfg, acc2[nt], 0, 0, 0);
        }
    }

    #pragma unroll
    for (int nt = 0; nt < 8; nt++) {
        #pragma unroll
        for (int r = 0; r < 4; r++) {
            int row = w * 16 + quad * 4 + r;
            float d = (float)(k0 + row) * hstep;
            float cut = 0.5f * (__cosf(d * pioc) + 1.0f);
            Tg[(size_t)(k0 + row) * 128 + nt * 16 + l15] = f2bf((acc2[nt][r] + b2v[nt]) * cut);
        }
    }
}

// ---------------------------------------------------------------------------
// Fully-fused SchNet: one block = one molecule, 512 threads = 8 waves.
// GEMM tile per wave: rows (w&1)*16, cols (w>>1)*32.
// Gather (R14 = R13 + scalar ko + pinned pipeline): channel-parallel dense
// pairs. ko loads are SCALAR (koW is a uniform pointer: blockIdx + rfl(w);
// constant offsets -> s_load into SGPRs, zero VALU/LDS for metadata; no LDS
// ko array at all). Two tp buffers (32 VGPR each); sched_barrier(0) after
// each TP_LOAD pins the issue order so chunk c+1's 32 table loads are in
// flight during chunk c's FMA body (R13's pipeline was silently re-serialized
// by the scheduler: VGPR_Count=56 proved tp buffers never co-lived).
// ---------------------------------------------------------------------------
__global__ __launch_bounds__(512, 4) void fused_schnet_kernel(
    const int* __restrict__ z, const float* __restrict__ emb,
    const unsigned* __restrict__ koG,
    const unsigned short* __restrict__ Tt,
    const unsigned short* __restrict__ Wtall,
    const float* __restrict__ cf2_b, const float* __restrict__ lin_b,
    const float* __restrict__ out1_b, const float* __restrict__ out2_w,
    const float* __restrict__ out2_b,
    float* __restrict__ out)
{
    __shared__ float s_h[32 * STRH];                 // 16.9 KB fp32 node state
    __shared__ float s_hx[32 * 128];                 // 16.4 KB fp32
    __shared__ unsigned short s_agg[32 * STRA];      //  8.7 KB bf16
    __shared__ float s_red;
    unsigned short* s_t = (unsigned short*)s_hx;     // [32][STRA] alias (8.7KB)

    const int tid  = threadIdx.x;
    const int lane = tid & 63;
    const int w    = tid >> 6;          // wave 0..7
    const int l15  = lane & 15;
    const int quad = lane >> 4;
    const int r16  = (w & 1) * 16;      // GEMM row tile
    const int c32  = (w >> 1) * 32;     // GEMM col tile
    const int B0   = blockIdx.x * 32;   // molecule base atom

    const unsigned lOff = (unsigned)(lane << 2);     // 4B into table row (2 bf16)

    // init h
    for (int i = tid; i < 32 * 128; i += 512) {
        int row = i >> 7, col = i & 127;
        s_h[row * STRH + col] = emb[(size_t)z[B0 + row] * 128 + col];
    }
    if (tid == 0) s_red = 0.0f;

    // wave-uniform knot-row pointer (4 dst rows of 32 src each) -> s_load
    const int wu = __builtin_amdgcn_readfirstlane(w);
    const unsigned* __restrict__ koW = koG + ((size_t)blockIdx.x << 10) + (wu << 7);

    const unsigned short* WtO = Wtall + 9 * 16384;   // out1^T

#define KO_SLOAD(KO, SC)                                                      \
    _Pragma("unroll")                                                         \
    for (int i = 0; i < 4; i++) {                                             \
        _Pragma("unroll")                                                     \
        for (int j = 0; j < 8; j++)                                           \
            KO[i][j] = koW[(i << 5) + ((SC) << 3) + j];                       \
    }
#define TP_LOAD(TP, KO)                                                       \
    _Pragma("unroll")                                                         \
    for (int i = 0; i < 4; i++) {                                             \
        _Pragma("unroll")                                                     \
        for (int j = 0; j < 8; j++)                                           \
            TP[i][j] = *(const unsigned*)(TlB + KO[i][j] + lOff);             \
    }
#define FMA_CHUNK(TP, SC)                                                     \
    _Pragma("unroll")                                                         \
    for (int j = 0; j < 8; j++) {                                             \
        float2 hv = *(const float2*)&s_hx[((((SC) << 3) + j) << 7) + (lane << 1)]; \
        _Pragma("unroll")                                                     \
        for (int i = 0; i < 4; i++) {                                         \
            unsigned t = TP[i][j];                                            \
            a0[i] = fmaf(hv.x, __uint_as_float(t << 16),         a0[i]);      \
            a1[i] = fmaf(hv.y, __uint_as_float(t & 0xffff0000u), a1[i]);      \
        }                                                                     \
    }

    for (int l = 0; l < 3; l++) {
        const unsigned short* W1 = Wtall + (size_t)(l * 3 + 0) * 16384;
        const unsigned short* W2 = Wtall + (size_t)(l * 3 + 1) * 16384;
        const unsigned short* W3 = Wtall + (size_t)(l * 3 + 2) * 16384;
        const char* TlB = (const char*)(Tt + (size_t)l * (KTAB + 1) * 128);

        // ---- pre-issue chunk-0 table loads (no dependency on s_h/s_hx) ----
        unsigned koA[4][8], koB[4][8], tpA[4][8], tpB[4][8];
        KO_SLOAD(koA, 0)
        TP_LOAD(tpA, koA)
        __builtin_amdgcn_sched_barrier(0);   // pin: tpA loads issue before GEMM1

        __syncthreads();   // h ready (GEMM3 of previous layer done)

        // ---- GEMM1: hx = h @ cf1 (16x32 tile per wave) ----
        floatx4 acc[2];
        #pragma unroll
        for (int nt = 0; nt < 2; nt++) acc[nt] = (floatx4){0.f, 0.f, 0.f, 0.f};
        #pragma unroll
        for (int ks = 0; ks < 4; ks++) {
            const float* hp = &s_h[(r16 + l15) * STRH + ks * 32 + quad * 8];
            float4 xa = *(const float4*)hp;
            float4 xb = *(const float4*)(hp + 4);
            unsigned int ap[4];
            ap[0] = pk2bf(xa.x, xa.y); ap[1] = pk2bf(xa.z, xa.w);
            ap[2] = pk2bf(xb.x, xb.y); ap[3] = pk2bf(xb.z, xb.w);
            short8 af;
            __builtin_memcpy(&af, ap, 16);
            #pragma unroll
            for (int nt = 0; nt < 2; nt++) {
                short8 bfg = *(const short8*)&W1[(size_t)(c32 + nt * 16 + l15) * 128 + ks * 32 + quad * 8];
                acc[nt] = __builtin_amdgcn_mfma_f32_16x16x32_bf16(af, bfg, acc[nt], 0, 0, 0);
            }
        }
        #pragma unroll
        for (int nt = 0; nt < 2; nt++) {
            #pragma unroll
            for (int r = 0; r < 4; r++)
                s_hx[(r16 + quad * 4 + r) * 128 + c32 + nt * 16 + l15] = acc[nt][r];
        }

        __syncthreads();   // hx complete before gather reads

        // ---- gather: dense pairs, 2-buffer pipelined chunks ----
        {
            float a0[4], a1[4];
            #pragma unroll
            for (int i = 0; i < 4; i++) { a0[i] = 0.0f; a1[i] = 0.0f; }

            KO_SLOAD(koB, 1)
            TP_LOAD(tpB, koB)
            __builtin_amdgcn_sched_barrier(0);   // tpB in flight over FMA(A)
            FMA_CHUNK(tpA, 0)

            KO_SLOAD(koA, 2)
            TP_LOAD(tpA, koA)
            __builtin_amdgcn_sched_barrier(0);
            FMA_CHUNK(tpB, 1)

            KO_SLOAD(koB, 3)
            TP_LOAD(tpB, koB)
            __builtin_amdgcn_sched_barrier(0);
            FMA_CHUNK(tpA, 2)

            FMA_CHUNK(tpB, 3)

            #pragma unroll
            for (int i = 0; i < 4; i++)
                *(unsigned*)&s_agg[((w << 2) + i) * STRA + (lane << 1)] = pk2bf(a0[i], a1[i]);
        }

        __syncthreads();   // agg complete; hx reads done (s_t alias safe)

        // ---- GEMM2: t = ssp(agg @ cf2 + b) ----
        float bva[2], bvb[2];
        #pragma unroll
        for (int nt = 0; nt < 2; nt++) {
            bva[nt] = cf2_b[l * 128 + c32 + nt * 16 + l15];
            bvb[nt] = lin_b[l * 128 + c32 + nt * 16 + l15];
        }
        #pragma unroll
        for (int nt = 0; nt < 2; nt++) acc[nt] = (floatx4){0.f, 0.f, 0.f, 0.f};
        #pragma unroll
        for (int ks = 0; ks < 4; ks++) {
            short8 af = *(const short8*)&s_agg[(r16 + l15) * STRA + ks * 32 + quad * 8];
            #pragma unroll
            for (int nt = 0; nt < 2; nt++) {
                short8 bfg = *(const short8*)&W2[(size_t)(c32 + nt * 16 + l15) * 128 + ks * 32 + quad * 8];
                acc[nt] = __builtin_amdgcn_mfma_f32_16x16x32_bf16(af, bfg, acc[nt], 0, 0, 0);
            }
        }
        #pragma unroll
        for (int nt = 0; nt < 2; nt++) {
            #pragma unroll
            for (int r = 0; r < 4; r++) {
                int row = r16 + quad * 4 + r;
                s_t[row * STRA + c32 + nt * 16 + l15] = f2bf(ssp(acc[nt][r] + bva[nt]));
            }
        }

        __syncthreads();   // t complete (cross-wave cols needed by GEMM3)

        // ---- GEMM3: h += t @ lin + b ----
        #pragma unroll
        for (int nt = 0; nt < 2; nt++) acc[nt] = (floatx4){0.f, 0.f, 0.f, 0.f};
        #pragma unroll
        for (int ks = 0; ks < 4; ks++) {
            short8 af = *(const short8*)&s_t[(r16 + l15) * STRA + ks * 32 + quad * 8];
            #pragma unroll
            for (int nt = 0; nt < 2; nt++) {
                short8 bfg = *(const short8*)&W3[(size_t)(c32 + nt * 16 + l15) * 128 + ks * 32 + quad * 8];
                acc[nt] = __builtin_amdgcn_mfma_f32_16x16x32_bf16(af, bfg, acc[nt], 0, 0, 0);
            }
        }
        #pragma unroll
        for (int nt = 0; nt < 2; nt++) {
            #pragma unroll
            for (int r = 0; r < 4; r++) {
                int row = r16 + quad * 4 + r;
                s_h[row * STRH + c32 + nt * 16 + l15] += acc[nt][r] + bvb[nt];
            }
        }
        // loop-top __syncthreads covers h
    }

    __syncthreads();

    // ---- head: out = sum_a ssp(h@out1 + b1)@out2 + 32*b2 ----
    const int c16 = (w >> 1) * 16;   // out1: 64 cols = 4 col tiles x 2 row tiles
    floatx4 ha = (floatx4){0.f, 0.f, 0.f, 0.f};
    #pragma unroll
    for (int ks = 0; ks < 4; ks++) {
        const float* hp = &s_h[(r16 + l15) * STRH + ks * 32 + quad * 8];
        float4 xa = *(const float4*)hp;
        float4 xb = *(const float4*)(hp + 4);
        unsigned int ap[4];
        ap[0] = pk2bf(xa.x, xa.y); ap[1] = pk2bf(xa.z, xa.w);
        ap[2] = pk2bf(xb.x, xb.y); ap[3] = pk2bf(xb.z, xb.w);
        short8 af;
        __builtin_memcpy(&af, ap, 16);
        short8 bfg = *(const short8*)&WtO[(size_t)(c16 + l15) * 128 + ks * 32 + quad * 8];
        ha = __builtin_amdgcn_mfma_f32_16x16x32_bf16(af, bfg, ha, 0, 0, 0);
    }
    float part = 0.0f;
    {
        float b1o = out1_b[c16 + l15];
        float o2  = out2_w[c16 + l15];
        #pragma unroll
        for (int r = 0; r < 4; r++)
            part += ssp(ha[r] + b1o) * o2;
    }
    #pragma unroll
    for (int off = 32; off > 0; off >>= 1) part += __shfl_down(part, off);
    if (lane == 0) atomicAdd(&s_red, part);
    __syncthreads();
    if (tid == 0) out[blockIdx.x] = s_red + 32.0f * out2_b[0];

#undef KO_SLOAD
#undef TP_LOAD
#undef FMA_CHUNK
}

extern "C" void kernel_launch(void* const* d_in, const int* in_sizes, int n_in,
                              void* d_out, int out_size, void* d_ws, size_t ws_size,
                              hipStream_t stream)
{
    const int*   z      = (const int*)d_in[0];
    const float* pos    = (const float*)d_in[1];
    const float* emb    = (const float*)d_in[4];
    const float* mlp_w1 = (const float*)d_in[5];
    const float* mlp_b1 = (const float*)d_in[6];
    const float* mlp_w2 = (const float*)d_in[7];
    const float* mlp_b2 = (const float*)d_in[8];
    const float* cf1_w  = (const float*)d_in[9];
    const float* cf2_w  = (const float*)d_in[10];
    const float* cf2_b  = (const float*)d_in[11];
    const float* lin_w  = (const float*)d_in[12];
    const float* lin_b  = (const float*)d_in[13];
    const float* out1_w = (const float*)d_in[14];
    const float* out1_b = (const float*)d_in[15];
    const float* out2_w = (const float*)d_in[16];
    const float* out2_b = (const float*)d_in[17];

    // workspace carve-up (16B-aligned sections)
    char* p = (char*)d_ws;
    unsigned* koG = (unsigned*)p;                 p += (size_t)NMOL * 1024 * 4;       // 2.0 MB
    unsigned short* Tt = (unsigned short*)p;      p += (size_t)3 * (KTAB + 1) * 128 * 2;
    unsigned short* Wtall = (unsigned short*)p;   // 9*16384 + 64*128 ushorts

    const int WB = (9 * 16384 + 64 * 128 + 255) / 256;
    const int TB = NTILE * 3;
    mega_setup_kernel<<<NMOL + WB + TB, 256, 0, stream>>>(
        pos, koG, cf1_w, cf2_w, lin_w, out1_w, Wtall,
        mlp_w1, mlp_b1, mlp_w2, mlp_b2, Tt);

    fused_schnet_kernel<<<NMOL, 512, 0, stream>>>(
        z, emb, koG, Tt, Wtall,
        cf2_b, lin_b, out1_b, out2_w, out2_b, (float*)d_out);
}

// Round 7
// 221.983 us; speedup vs baseline: 1.7391x; 1.7391x over previous
//
#include <hip/hip_runtime.h>
#include <hip/hip_bf16.h>
#include <math.h>

// Problem constants (SchNet reference)
#define NATOMS 16384
#define NMOL   512
#define APM    32
#define GDIM   50
#define KTAB   4096   // filter lookup-table knots over d in [0,6] (nearest-knot)

#define STRH 132      // s_h row stride (floats), 528B
#define STRA 136      // s_agg / s_t row stride (ushorts), 272B

typedef __attribute__((ext_vector_type(8))) short   short8;   // 8 bf16 (A/B frag)
typedef __attribute__((ext_vector_type(4))) float   floatx4;  // C/D frag

// fast shifted softplus: log(1+exp(x)) - log2, via HW v_exp_f32/v_log_f32
__device__ __forceinline__ float ssp(float x) {
    float e = __expf(-fabsf(x));
    return fmaxf(x, 0.0f) + __logf(1.0f + e) - 0.69314718055994531f;
}

__device__ __forceinline__ unsigned short f2bf(float x) {
    union { float f; unsigned int u; } v; v.f = x;
    unsigned int lsb = (v.u >> 16) & 1u;
    v.u += 0x7fffu + lsb;
    return (unsigned short)(v.u >> 16);
}

__device__ __forceinline__ unsigned int pk2bf(float a, float b) {
    __hip_bfloat162 h = __float22bfloat162_rn(make_float2(a, b));
    unsigned int u;
    __builtin_memcpy(&u, &h, 4);
    return u;
}

// ---------------------------------------------------------------------------
// MEGA-SETUP (single dispatch, 3 block regions):
//  [0,NMOL):       dense pair-knot table koG[mol][dst][src] (byte offsets,
//                  sentinel = zero-row) computed straight from positions
//                  (edge set == {d<=6, i!=j}; boundary edges have weight ~0).
//                  Blocks 0..2 also zero the sentinel table rows.
//  [NMOL,+WB):     weights fp32 -> bf16 B-frag transpose (9x128x128 + out1)
//  [NMOL+WB,+192): filter table, 64 tiles x 3 layers, plain bf16 rows:
//                  T[l][k][f] = ((ssp(ea(d_k)@w1+b1)@w2)+b2)*cut(d_k)
//  Each layer has KTAB+1 rows; row KTAB is all-zero (dense-gather sentinel).
// ---------------------------------------------------------------------------
#define KW1 72
#define KW2 136
#define NTILE (KTAB / 64)   // 64 tiles per layer

__global__ __launch_bounds__(256) void mega_setup_kernel(
    const float* __restrict__ pos,
    unsigned* __restrict__ koG,
    const float* __restrict__ cf1, const float* __restrict__ cf2,
    const float* __restrict__ lin, const float* __restrict__ out1,
    unsigned short* __restrict__ Wtall,
    const float* __restrict__ w1_, const float* __restrict__ b1_,
    const float* __restrict__ w2_, const float* __restrict__ b2_,
    unsigned short* __restrict__ Tt)
{
    const int WB = (9 * 16384 + 64 * 128 + 255) / 256;
    const int b = blockIdx.x;
    const int tid = threadIdx.x;

    __shared__ float sp[96];

    if (b < NMOL) {
        // ---- dense koG for molecule b ----
        if (tid < 96) sp[tid] = pos[b * 96 + tid];
        if (b < 3 && tid < 128)
            Tt[(size_t)b * (KTAB + 1) * 128 + (size_t)KTAB * 128 + tid] = 0;  // zero row
        __syncthreads();
        #pragma unroll
        for (int c4 = 0; c4 < 4; c4++) {
            int c = c4 * 256 + tid;
            int i = c >> 5, j = c & 31;          // dst i, src j
            float dx = sp[3 * i]     - sp[3 * j];
            float dy = sp[3 * i + 1] - sp[3 * j + 1];
            float dz = sp[3 * i + 2] - sp[3 * j + 2];
            float d  = sqrtf(dx * dx + dy * dy + dz * dz);
            unsigned off = (unsigned)(KTAB << 8);      // sentinel: zero row
            if (i != j && d <= 6.0f) {
                float u = d * (float)(KTAB - 1) / 6.0f;
                int k = min((int)(u + 0.5f), KTAB - 1);
                off = (unsigned)(k << 8);
            }
            koG[((size_t)b << 10) + c] = off;
        }
        return;
    }
    if (b < NMOL + WB) {
        int idx = (b - NMOL) * 256 + tid;
        if (idx < 9 * 16384) {
            int wi = idx >> 14, rem = idx & 16383;
            int n = rem >> 7, k = rem & 127;
            int l = wi / 3, which = wi % 3;
            const float* src = (which == 0) ? cf1 : (which == 1) ? cf2 : lin;
            Wtall[idx] = f2bf(src[(size_t)l * 16384 + k * 128 + n]);
        } else if (idx < 9 * 16384 + 64 * 128) {
            int q = idx - 9 * 16384;
            int n = q >> 7, k = q & 127;
            Wtall[idx] = f2bf(out1[k * 64 + n]);
        }
        return;
    }

    // ---------------- table region: tt = (layer, tile) ----------------
    __shared__ unsigned short s_bufA[128 * KW2];   // w2T
    __shared__ unsigned short s_bufB[128 * KW1];   // w1T, then s_t (alias)

    const int tt = b - NMOL - WB;
    const int l  = tt / NTILE;
    const int bx = tt % NTILE;
    const float* w1 = w1_ + (size_t)l * GDIM * 128;
    const float* b1 = b1_ + (size_t)l * 128;
    const float* w2 = w2_ + (size_t)l * 128 * 128;
    const float* b2 = b2_ + (size_t)l * 128;
    unsigned short* Tg = Tt + (size_t)l * (KTAB + 1) * 128;

    unsigned short* s_w1T = s_bufB;                // [128][KW1]
    unsigned short* s_w2T = s_bufA;                // [128][KW2]
    unsigned short* s_t   = s_bufB;                // [64][KW2] (after barrier)

    for (int i = tid; i < GDIM * 128; i += 256) {
        int g = i >> 7, f = i & 127;
        s_w1T[f * KW1 + g] = f2bf(w1[i]);
    }
    for (int i = tid; i < (64 - GDIM) * 128; i += 256) {
        int g = GDIM + (i >> 7), f = i & 127;
        s_w1T[f * KW1 + g] = 0;
    }
    for (int i = tid; i < 128 * 128; i += 256) {
        int k = i >> 7, n = i & 127;
        s_w2T[n * KW2 + k] = f2bf(w2[i]);
    }

    const int lane = tid & 63;
    const int w    = tid >> 6;
    const int l15  = lane & 15;
    const int quad = lane >> 4;

    float b1v[8], b2v[8];
    #pragma unroll
    for (int nt = 0; nt < 8; nt++) {
        b1v[nt] = b1[nt * 16 + l15];
        b2v[nt] = b2[nt * 16 + l15];
    }
    __syncthreads();

    const float hstep = 6.0f / (float)(KTAB - 1);
    const float step  = 6.0f / 49.0f;
    const float coeff = -0.5f / (step * step);
    const float pioc  = 3.14159265358979323846f / 6.0f;
    const int k0 = bx * 64;
    const float dm = (float)(k0 + w * 16 + l15) * hstep;

    floatx4 acc1[8];
    #pragma unroll
    for (int nt = 0; nt < 8; nt++) acc1[nt] = (floatx4){0.f, 0.f, 0.f, 0.f};
    #pragma unroll
    for (int ks = 0; ks < 2; ks++) {
        unsigned int ap[4];
        #pragma unroll
        for (int jj = 0; jj < 4; jj++) {
            int g0 = ks * 32 + quad * 8 + 2 * jj;
            float d0 = dm - (float)g0 * step;
            float d1 = dm - (float)(g0 + 1) * step;
            float v0 = (g0 < GDIM)     ? __expf(coeff * d0 * d0) : 0.0f;
            float v1 = (g0 + 1 < GDIM) ? __expf(coeff * d1 * d1) : 0.0f;
            ap[jj] = pk2bf(v0, v1);
        }
        short8 af;
        __builtin_memcpy(&af, ap, 16);
        #pragma unroll
        for (int nt = 0; nt < 8; nt++) {
            short8 bfg = *(const short8*)&s_w1T[(nt * 16 + l15) * KW1 + ks * 32 + quad * 8];
            acc1[nt] = __builtin_amdgcn_mfma_f32_16x16x32_bf16(af, bfg, acc1[nt], 0, 0, 0);
        }
    }
    __syncthreads();   // all waves done reading s_w1T; s_t may alias it

    #pragma unroll
    for (int nt = 0; nt < 8; nt++) {
        #pragma unroll
        for (int r = 0; r < 4; r++) {
            int row = w * 16 + quad * 4 + r;
            s_t[row * KW2 + nt * 16 + l15] = f2bf(ssp(acc1[nt][r] + b1v[nt]));
        }
    }
    // no barrier: wave reads only rows it wrote

    floatx4 acc2[8];
    #pragma unroll
    for (int nt = 0; nt < 8; nt++) acc2[nt] = (floatx4){0.f, 0.f, 0.f, 0.f};
    #pragma unroll
    for (int ks = 0; ks < 4; ks++) {
        short8 af = *(const short8*)&s_t[(w * 16 + l15) * KW2 + ks * 32 + quad * 8];
        #pragma unroll
        for (int nt = 0; nt < 8; nt++) {
            short8 bfg = *(const short8*)&s_w2T[(nt * 16 + l15) * KW2 + ks * 32 + quad * 8];
            acc2[nt] = __builtin_amdgcn_mfma_f32_16x16x32_bf16(af, bfg, acc2[nt], 0, 0, 0);
        }
    }

    #pragma unroll
    for (int nt = 0; nt < 8; nt++) {
        #pragma unroll
        for (int r = 0; r < 4; r++) {
            int row = w * 16 + quad * 4 + r;
            float d = (float)(k0 + row) * hstep;
            float cut = 0.5f * (__cosf(d * pioc) + 1.0f);
            Tg[(size_t)(k0 + row) * 128 + nt * 16 + l15] = f2bf((acc2[nt][r] + b2v[nt]) * cut);
        }
    }
}

// ---------------------------------------------------------------------------
// Fully-fused SchNet: one block = one molecule, 512 threads = 8 waves.
// GEMM tile per wave: rows (w&1)*16, cols (w>>1)*32.
// Gather (R15 = R5 base + T3/T4-style cross-barrier prefetch):
//  * ko via SCALAR loads from uniform koW pointer (s_load, 0 VALU, 0 LDS;
//    replaces R5's 32 ds_read_b128 + 384 readfirstlane per wave).
//  * RAW s_barrier + explicit "s_waitcnt lgkmcnt(0)" at the 4 phase
//    boundaries (A:h, B:hx, C:agg, D:t). __syncthreads' vmcnt(0) drain is
//    what killed every prior prefetch; raw barriers let global loads stay
//    in flight across phases. NO sched_barrier (R4/R6 pin->spill lesson).
//  * tp chunk-0 (32 loads) issued BEFORE barrier A -> latency hidden under
//    GEMM1 + barrier B. W2/W3 fragments + biases issued before C/D.
//  LDS hazard audit: A covers GEMM3 s_h writes; B covers s_hx writes;
//  C covers s_agg writes AND retires gather's hx reads before the s_t
//  alias is overwritten; D covers s_t writes. Init/head keep __syncthreads.
// ---------------------------------------------------------------------------
__global__ __launch_bounds__(512, 4) void fused_schnet_kernel(
    const int* __restrict__ z, const float* __restrict__ emb,
    const unsigned* __restrict__ koG,
    const unsigned short* __restrict__ Tt,
    const unsigned short* __restrict__ Wtall,
    const float* __restrict__ cf2_b, const float* __restrict__ lin_b,
    const float* __restrict__ out1_b, const float* __restrict__ out2_w,
    const float* __restrict__ out2_b,
    float* __restrict__ out)
{
    __shared__ float s_h[32 * STRH];                 // 16.9 KB fp32 node state
    __shared__ float s_hx[32 * 128];                 // 16.4 KB fp32
    __shared__ unsigned short s_agg[32 * STRA];      //  8.7 KB bf16
    __shared__ float s_red;
    unsigned short* s_t = (unsigned short*)s_hx;     // [32][STRA] alias (8.7KB)

    const int tid  = threadIdx.x;
    const int lane = tid & 63;
    const int w    = tid >> 6;          // wave 0..7
    const int l15  = lane & 15;
    const int quad = lane >> 4;
    const int r16  = (w & 1) * 16;      // GEMM row tile
    const int c32  = (w >> 1) * 32;     // GEMM col tile
    const int B0   = blockIdx.x * 32;   // molecule base atom

    const unsigned lOff = (unsigned)(lane << 2);     // 4B into table row (2 bf16)

    // init h
    for (int i = tid; i < 32 * 128; i += 512) {
        int row = i >> 7, col = i & 127;
        s_h[row * STRH + col] = emb[(size_t)z[B0 + row] * 128 + col];
    }
    if (tid == 0) s_red = 0.0f;

    // wave-uniform knot-row pointer (4 dst rows of 32 src each) -> s_load
    const int wu = __builtin_amdgcn_readfirstlane(w);
    const unsigned* __restrict__ koW = koG + ((size_t)blockIdx.x << 10) + (wu << 7);

    const unsigned short* WtO = Wtall + 9 * 16384;   // out1^T

    __syncthreads();   // init (s_h) visible to all waves

#define KO_SLOAD(KO, SC)                                                      \
    _Pragma("unroll")                                                         \
    for (int i = 0; i < 4; i++) {                                             \
        _Pragma("unroll")                                                     \
        for (int j = 0; j < 8; j++)                                           \
            KO[i][j] = koW[(i << 5) + ((SC) << 3) + j];                       \
    }
#define TP_LOAD(TP, KO)                                                       \
    _Pragma("unroll")                                                         \
    for (int i = 0; i < 4; i++) {                                             \
        _Pragma("unroll")                                                     \
        for (int j = 0; j < 8; j++)                                           \
            TP[i][j] = *(const unsigned*)(TlB + KO[i][j] + lOff);             \
    }
#define FMA_CHUNK(TP, SC)                                                     \
    _Pragma("unroll")                                                         \
    for (int j = 0; j < 8; j++) {                                             \
        float2 hv = *(const float2*)&s_hx[((((SC) << 3) + j) << 7) + (lane << 1)]; \
        _Pragma("unroll")                                                     \
        for (int i = 0; i < 4; i++) {                                         \
            unsigned t = TP[i][j];                                            \
            a0[i] = fmaf(hv.x, __uint_as_float(t << 16),         a0[i]);      \
            a1[i] = fmaf(hv.y, __uint_as_float(t & 0xffff0000u), a1[i]);      \
        }                                                                     \
    }
#define PHASE_BARRIER()                                                       \
    asm volatile("s_waitcnt lgkmcnt(0)" ::: "memory");                        \
    __builtin_amdgcn_s_barrier();

    for (int l = 0; l < 3; l++) {
        const unsigned short* W1 = Wtall + (size_t)(l * 3 + 0) * 16384;
        const unsigned short* W2 = Wtall + (size_t)(l * 3 + 1) * 16384;
        const unsigned short* W3 = Wtall + (size_t)(l * 3 + 2) * 16384;
        const char* TlB = (const char*)(Tt + (size_t)l * (KTAB + 1) * 128);

        // ---- pre-issue: chunk-0 table loads + chunk-1 ko (no LDS deps) ----
        unsigned koA[4][8], koB[4][8], tpA[4][8], tpB[4][8];
        KO_SLOAD(koA, 0)
        TP_LOAD(tpA, koA)        // stays in flight across A, GEMM1, B
        KO_SLOAD(koB, 1)

        PHASE_BARRIER()          // A: h ready (covers GEMM3 s_h writes)

        // ---- GEMM1: hx = h @ cf1 (16x32 tile per wave) ----
        floatx4 acc[2];
        #pragma unroll
        for (int nt = 0; nt < 2; nt++) acc[nt] = (floatx4){0.f, 0.f, 0.f, 0.f};
        #pragma unroll
        for (int ks = 0; ks < 4; ks++) {
            const float* hp = &s_h[(r16 + l15) * STRH + ks * 32 + quad * 8];
            float4 xa = *(const float4*)hp;
            float4 xb = *(const float4*)(hp + 4);
            unsigned int ap[4];
            ap[0] = pk2bf(xa.x, xa.y); ap[1] = pk2bf(xa.z, xa.w);
            ap[2] = pk2bf(xb.x, xb.y); ap[3] = pk2bf(xb.z, xb.w);
            short8 af;
            __builtin_memcpy(&af, ap, 16);
            #pragma unroll
            for (int nt = 0; nt < 2; nt++) {
                short8 bfg = *(const short8*)&W1[(size_t)(c32 + nt * 16 + l15) * 128 + ks * 32 + quad * 8];
                acc[nt] = __builtin_amdgcn_mfma_f32_16x16x32_bf16(af, bfg, acc[nt], 0, 0, 0);
            }
        }
        #pragma unroll
        for (int nt = 0; nt < 2; nt++) {
            #pragma unroll
            for (int r = 0; r < 4; r++)
                s_hx[(r16 + quad * 4 + r) * 128 + c32 + nt * 16 + l15] = acc[nt][r];
        }

        PHASE_BARRIER()          // B: hx ready (covers s_hx writes)

        // ---- gather: dense pairs, 2-buffer chunks; tpA already in flight ----
        {
            float a0[4], a1[4];
            #pragma unroll
            for (int i = 0; i < 4; i++) { a0[i] = 0.0f; a1[i] = 0.0f; }

            TP_LOAD(tpB, koB)    // ko1 arrived long ago; tpB in flight
            KO_SLOAD(koA, 2)
            FMA_CHUNK(tpA, 0)    // waits only tpA (counted vmcnt, automatic)

            TP_LOAD(tpA, koA)
            KO_SLOAD(koB, 3)
            FMA_CHUNK(tpB, 1)

            TP_LOAD(tpB, koB)
            FMA_CHUNK(tpA, 2)

            FMA_CHUNK(tpB, 3)

            #pragma unroll
            for (int i = 0; i < 4; i++)
                *(unsigned*)&s_agg[((w << 2) + i) * STRA + (lane << 1)] = pk2bf(a0[i], a1[i]);
        }

        // ---- pre-issue GEMM2 operands (global; independent of LDS) ----
        short8 w2f[2][4];
        float bva[2], bvb[2];
        #pragma unroll
        for (int nt = 0; nt < 2; nt++) {
            #pragma unroll
            for (int ks = 0; ks < 4; ks++)
                w2f[nt][ks] = *(const short8*)&W2[(size_t)(c32 + nt * 16 + l15) * 128 + ks * 32 + quad * 8];
            bva[nt] = cf2_b[l * 128 + c32 + nt * 16 + l15];
            bvb[nt] = lin_b[l * 128 + c32 + nt * 16 + l15];
        }

        PHASE_BARRIER()          // C: agg ready; gather's hx reads retired

        // ---- GEMM2: t = ssp(agg @ cf2 + b) ----
        #pragma unroll
        for (int nt = 0; nt < 2; nt++) acc[nt] = (floatx4){0.f, 0.f, 0.f, 0.f};
        #pragma unroll
        for (int ks = 0; ks < 4; ks++) {
            short8 af = *(const short8*)&s_agg[(r16 + l15) * STRA + ks * 32 + quad * 8];
            #pragma unroll
            for (int nt = 0; nt < 2; nt++)
                acc[nt] = __builtin_amdgcn_mfma_f32_16x16x32_bf16(af, w2f[nt][ks], acc[nt], 0, 0, 0);
        }
        #pragma unroll
        for (int nt = 0; nt < 2; nt++) {
            #pragma unroll
            for (int r = 0; r < 4; r++) {
                int row = r16 + quad * 4 + r;
                s_t[row * STRA + c32 + nt * 16 + l15] = f2bf(ssp(acc[nt][r] + bva[nt]));
            }
        }

        // ---- pre-issue GEMM3 operands ----
        short8 w3f[2][4];
        #pragma unroll
        for (int nt = 0; nt < 2; nt++) {
            #pragma unroll
            for (int ks = 0; ks < 4; ks++)
                w3f[nt][ks] = *(const short8*)&W3[(size_t)(c32 + nt * 16 + l15) * 128 + ks * 32 + quad * 8];
        }

        PHASE_BARRIER()          // D: t ready (covers s_t writes)

        // ---- GEMM3: h += t @ lin + b ----
        #pragma unroll
        for (int nt = 0; nt < 2; nt++) acc[nt] = (floatx4){0.f, 0.f, 0.f, 0.f};
        #pragma unroll
        for (int ks = 0; ks < 4; ks++) {
            short8 af = *(const short8*)&s_t[(r16 + l15) * STRA + ks * 32 + quad * 8];
            #pragma unroll
            for (int nt = 0; nt < 2; nt++)
                acc[nt] = __builtin_amdgcn_mfma_f32_16x16x32_bf16(af, w3f[nt][ks], acc[nt], 0, 0, 0);
        }
        #pragma unroll
        for (int nt = 0; nt < 2; nt++) {
            #pragma unroll
            for (int r = 0; r < 4; r++) {
                int row = r16 + quad * 4 + r;
                s_h[row * STRH + c32 + nt * 16 + l15] += acc[nt][r] + bvb[nt];
            }
        }
        // next-layer barrier A covers s_h updates
    }

    __syncthreads();   // full drain before head

    // ---- head: out = sum_a ssp(h@out1 + b1)@out2 + 32*b2 ----
    const int c16 = (w >> 1) * 16;   // out1: 64 cols = 4 col tiles x 2 row tiles
    floatx4 ha = (floatx4){0.f, 0.f, 0.f, 0.f};
    #pragma unroll
    for (int ks = 0; ks < 4; ks++) {
        const float* hp = &s_h[(r16 + l15) * STRH + ks * 32 + quad * 8];
        float4 xa = *(const float4*)hp;
        float4 xb = *(const float4*)(hp + 4);
        unsigned int ap[4];
        ap[0] = pk2bf(xa.x, xa.y); ap[1] = pk2bf(xa.z, xa.w);
        ap[2] = pk2bf(xb.x, xb.y); ap[3] = pk2bf(xb.z, xb.w);
        short8 af;
        __builtin_memcpy(&af, ap, 16);
        short8 bfg = *(const short8*)&WtO[(size_t)(c16 + l15) * 128 + ks * 32 + quad * 8];
        ha = __builtin_amdgcn_mfma_f32_16x16x32_bf16(af, bfg, ha, 0, 0, 0);
    }
    float part = 0.0f;
    {
        float b1o = out1_b[c16 + l15];
        float o2  = out2_w[c16 + l15];
        #pragma unroll
        for (int r = 0; r < 4; r++)
            part += ssp(ha[r] + b1o) * o2;
    }
    #pragma unroll
    for (int off = 32; off > 0; off >>= 1) part += __shfl_down(part, off);
    if (lane == 0) atomicAdd(&s_red, part);
    __syncthreads();
    if (tid == 0) out[blockIdx.x] = s_red + 32.0f * out2_b[0];

#undef KO_SLOAD
#undef TP_LOAD
#undef FMA_CHUNK
#undef PHASE_BARRIER
}

extern "C" void kernel_launch(void* const* d_in, const int* in_sizes, int n_in,
                              void* d_out, int out_size, void* d_ws, size_t ws_size,
                              hipStream_t stream)
{
    const int*   z      = (const int*)d_in[0];
    const float* pos    = (const float*)d_in[1];
    const float* emb    = (const float*)d_in[4];
    const float* mlp_w1 = (const float*)d_in[5];
    const float* mlp_b1 = (const float*)d_in[6];
    const float* mlp_w2 = (const float*)d_in[7];
    const float* mlp_b2 = (const float*)d_in[8];
    const float* cf1_w  = (const float*)d_in[9];
    const float* cf2_w  = (const float*)d_in[10];
    const float* cf2_b  = (const float*)d_in[11];
    const float* lin_w  = (const float*)d_in[12];
    const float* lin_b  = (const float*)d_in[13];
    const float* out1_w = (const float*)d_in[14];
    const float* out1_b = (const float*)d_in[15];
    const float* out2_w = (const float*)d_in[16];
    const float* out2_b = (const float*)d_in[17];

    // workspace carve-up (16B-aligned sections)
    char* p = (char*)d_ws;
    unsigned* koG = (unsigned*)p;                 p += (size_t)NMOL * 1024 * 4;       // 2.0 MB
    unsigned short* Tt = (unsigned short*)p;      p += (size_t)3 * (KTAB + 1) * 128 * 2;
    unsigned short* Wtall = (unsigned short*)p;   // 9*16384 + 64*128 ushorts

    const int WB = (9 * 16384 + 64 * 128 + 255) / 256;
    const int TB = NTILE * 3;
    mega_setup_kernel<<<NMOL + WB + TB, 256, 0, stream>>>(
        pos, koG, cf1_w, cf2_w, lin_w, out1_w, Wtall,
        mlp_w1, mlp_b1, mlp_w2, mlp_b2, Tt);

    fused_schnet_kernel<<<NMOL, 512, 0, stream>>>(
        z, emb, koG, Tt, Wtall,
        cf2_b, lin_b, out1_b, out2_w, out2_b, (float*)d_out);
}

// Round 8
// 188.462 us; speedup vs baseline: 2.0485x; 1.1779x over previous
//
#include <hip/hip_runtime.h>
#include <hip/hip_bf16.h>
#include <math.h>

// Problem constants (SchNet reference)
#define NATOMS 16384
#define NMOL   512
#define APM    32
#define GDIM   50
#define KTAB   4096   // filter lookup-table knots over d in [0,6] (nearest-knot)

#define STRH 132      // s_h row stride (floats), 528B
#define STRA 136      // s_agg / s_t row stride (ushorts), 272B

typedef __attribute__((ext_vector_type(8))) short   short8;   // 8 bf16 (A/B frag)
typedef __attribute__((ext_vector_type(4))) float   floatx4;  // C/D frag
typedef __attribute__((ext_vector_type(2))) float   floatx2;  // packed f32 pair

// fast shifted softplus: log(1+exp(x)) - log2, via HW v_exp_f32/v_log_f32
__device__ __forceinline__ float ssp(float x) {
    float e = __expf(-fabsf(x));
    return fmaxf(x, 0.0f) + __logf(1.0f + e) - 0.69314718055994531f;
}

__device__ __forceinline__ unsigned short f2bf(float x) {
    union { float f; unsigned int u; } v; v.f = x;
    unsigned int lsb = (v.u >> 16) & 1u;
    v.u += 0x7fffu + lsb;
    return (unsigned short)(v.u >> 16);
}

__device__ __forceinline__ unsigned int pk2bf(float a, float b) {
    __hip_bfloat162 h = __float22bfloat162_rn(make_float2(a, b));
    unsigned int u;
    __builtin_memcpy(&u, &h, 4);
    return u;
}

// ---------------------------------------------------------------------------
// MEGA-SETUP (single dispatch, 3 block regions):
//  [0,NMOL):       dense pair-knot table koG[mol][dst][src] (BYTE offsets into
//                  the fp32 table: k<<9; sentinel = zero-row) computed straight
//                  from positions. Blocks 0..2 zero the sentinel rows.
//  [NMOL,+WB):     weights fp32 -> bf16 B-frag transpose (9x128x128 + out1)
//  [NMOL+WB,+192): filter table, 64 tiles x 3 layers, FP32 rows (R8: fp32 so
//                  the gather needs no bf16 unpack and can use v_pk_fma_f32):
//                  T[l][k][f] = ((ssp(ea(d_k)@w1+b1)@w2)+b2)*cut(d_k)
//  Each layer has KTAB+1 rows; row KTAB is all-zero (dense-gather sentinel).
// ---------------------------------------------------------------------------
#define KW1 72
#define KW2 136
#define NTILE (KTAB / 64)   // 64 tiles per layer

__global__ __launch_bounds__(256) void mega_setup_kernel(
    const float* __restrict__ pos,
    unsigned* __restrict__ koG,
    const float* __restrict__ cf1, const float* __restrict__ cf2,
    const float* __restrict__ lin, const float* __restrict__ out1,
    unsigned short* __restrict__ Wtall,
    const float* __restrict__ w1_, const float* __restrict__ b1_,
    const float* __restrict__ w2_, const float* __restrict__ b2_,
    float* __restrict__ Tt)
{
    const int WB = (9 * 16384 + 64 * 128 + 255) / 256;
    const int b = blockIdx.x;
    const int tid = threadIdx.x;

    __shared__ float sp[96];

    if (b < NMOL) {
        // ---- dense koG for molecule b ----
        if (tid < 96) sp[tid] = pos[b * 96 + tid];
        if (b < 3 && tid < 128)
            Tt[(size_t)b * (KTAB + 1) * 128 + (size_t)KTAB * 128 + tid] = 0.0f;  // zero row
        __syncthreads();
        #pragma unroll
        for (int c4 = 0; c4 < 4; c4++) {
            int c = c4 * 256 + tid;
            int i = c >> 5, j = c & 31;          // dst i, src j
            float dx = sp[3 * i]     - sp[3 * j];
            float dy = sp[3 * i + 1] - sp[3 * j + 1];
            float dz = sp[3 * i + 2] - sp[3 * j + 2];
            float d  = sqrtf(dx * dx + dy * dy + dz * dz);
            unsigned off = (unsigned)(KTAB << 9);      // sentinel: zero row
            if (i != j && d <= 6.0f) {
                float u = d * (float)(KTAB - 1) / 6.0f;
                int k = min((int)(u + 0.5f), KTAB - 1);
                off = (unsigned)(k << 9);
            }
            koG[((size_t)b << 10) + c] = off;
        }
        return;
    }
    if (b < NMOL + WB) {
        int idx = (b - NMOL) * 256 + tid;
        if (idx < 9 * 16384) {
            int wi = idx >> 14, rem = idx & 16383;
            int n = rem >> 7, k = rem & 127;
            int l = wi / 3, which = wi % 3;
            const float* src = (which == 0) ? cf1 : (which == 1) ? cf2 : lin;
            Wtall[idx] = f2bf(src[(size_t)l * 16384 + k * 128 + n]);
        } else if (idx < 9 * 16384 + 64 * 128) {
            int q = idx - 9 * 16384;
            int n = q >> 7, k = q & 127;
            Wtall[idx] = f2bf(out1[k * 64 + n]);
        }
        return;
    }

    // ---------------- table region: tt = (layer, tile) ----------------
    __shared__ unsigned short s_bufA[128 * KW2];   // w2T
    __shared__ unsigned short s_bufB[128 * KW1];   // w1T, then s_t (alias)

    const int tt = b - NMOL - WB;
    const int l  = tt / NTILE;
    const int bx = tt % NTILE;
    const float* w1 = w1_ + (size_t)l * GDIM * 128;
    const float* b1 = b1_ + (size_t)l * 128;
    const float* w2 = w2_ + (size_t)l * 128 * 128;
    const float* b2 = b2_ + (size_t)l * 128;
    float* Tg = Tt + (size_t)l * (KTAB + 1) * 128;

    unsigned short* s_w1T = s_bufB;                // [128][KW1]
    unsigned short* s_w2T = s_bufA;                // [128][KW2]
    unsigned short* s_t   = s_bufB;                // [64][KW2] (after barrier)

    for (int i = tid; i < GDIM * 128; i += 256) {
        int g = i >> 7, f = i & 127;
        s_w1T[f * KW1 + g] = f2bf(w1[i]);
    }
    for (int i = tid; i < (64 - GDIM) * 128; i += 256) {
        int g = GDIM + (i >> 7), f = i & 127;
        s_w1T[f * KW1 + g] = 0;
    }
    for (int i = tid; i < 128 * 128; i += 256) {
        int k = i >> 7, n = i & 127;
        s_w2T[n * KW2 + k] = f2bf(w2[i]);
    }

    const int lane = tid & 63;
    const int w    = tid >> 6;
    const int l15  = lane & 15;
    const int quad = lane >> 4;

    float b1v[8], b2v[8];
    #pragma unroll
    for (int nt = 0; nt < 8; nt++) {
        b1v[nt] = b1[nt * 16 + l15];
        b2v[nt] = b2[nt * 16 + l15];
    }
    __syncthreads();

    const float hstep = 6.0f / (float)(KTAB - 1);
    const float step  = 6.0f / 49.0f;
    const float coeff = -0.5f / (step * step);
    const float pioc  = 3.14159265358979323846f / 6.0f;
    const int k0 = bx * 64;
    const float dm = (float)(k0 + w * 16 + l15) * hstep;

    floatx4 acc1[8];
    #pragma unroll
    for (int nt = 0; nt < 8; nt++) acc1[nt] = (floatx4){0.f, 0.f, 0.f, 0.f};
    #pragma unroll
    for (int ks = 0; ks < 2; ks++) {
        unsigned int ap[4];
        #pragma unroll
        for (int jj = 0; jj < 4; jj++) {
            int g0 = ks * 32 + quad * 8 + 2 * jj;
            float d0 = dm - (float)g0 * step;
            float d1 = dm - (float)(g0 + 1) * step;
            float v0 = (g0 < GDIM)     ? __expf(coeff * d0 * d0) : 0.0f;
            float v1 = (g0 + 1 < GDIM) ? __expf(coeff * d1 * d1) : 0.0f;
            ap[jj] = pk2bf(v0, v1);
        }
        short8 af;
        __builtin_memcpy(&af, ap, 16);
        #pragma unroll
        for (int nt = 0; nt < 8; nt++) {
            short8 bfg = *(const short8*)&s_w1T[(nt * 16 + l15) * KW1 + ks * 32 + quad * 8];
            acc1[nt] = __builtin_amdgcn_mfma_f32_16x16x32_bf16(af, bfg, acc1[nt], 0, 0, 0);
        }
    }
    __syncthreads();   // all waves done reading s_w1T; s_t may alias it

    #pragma unroll
    for (int nt = 0; nt < 8; nt++) {
        #pragma unroll
        for (int r = 0; r < 4; r++) {
            int row = w * 16 + quad * 4 + r;
            s_t[row * KW2 + nt * 16 + l15] = f2bf(ssp(acc1[nt][r] + b1v[nt]));
        }
    }
    // no barrier: wave reads only rows it wrote

    floatx4 acc2[8];
    #pragma unroll
    for (int nt = 0; nt < 8; nt++) acc2[nt] = (floatx4){0.f, 0.f, 0.f, 0.f};
    #pragma unroll
    for (int ks = 0; ks < 4; ks++) {
        short8 af = *(const short8*)&s_t[(w * 16 + l15) * KW2 + ks * 32 + quad * 8];
        #pragma unroll
        for (int nt = 0; nt < 8; nt++) {
            short8 bfg = *(const short8*)&s_w2T[(nt * 16 + l15) * KW2 + ks * 32 + quad * 8];
            acc2[nt] = __builtin_amdgcn_mfma_f32_16x16x32_bf16(af, bfg, acc2[nt], 0, 0, 0);
        }
    }

    #pragma unroll
    for (int nt = 0; nt < 8; nt++) {
        #pragma unroll
        for (int r = 0; r < 4; r++) {
            int row = w * 16 + quad * 4 + r;
            float d = (float)(k0 + row) * hstep;
            float cut = 0.5f * (__cosf(d * pioc) + 1.0f);
            Tg[(size_t)(k0 + row) * 128 + nt * 16 + l15] = (acc2[nt][r] + b2v[nt]) * cut;
        }
    }
}

// ---------------------------------------------------------------------------
// Fully-fused SchNet: one block = one molecule, 512 threads = 8 waves.
// GEMM tile per wave: rows (w&1)*16, cols (w>>1)*32.
// Gather (R16 = R5 structure + fp32 table + packed FMA):
//  * FP32 filter table: tp load = global_load_dwordx2 of 2 ready floats ->
//    NO bf16 unpack (was 2 VALU/pair), and one v_pk_fma_f32 does both
//    channels (halves FMA count). Per (dst,src) per lane: 1 v_add (voffset)
//    + 1 load + 1 pk_fma vs R5's rfl + load + 2 unpack + 2 fma.
//  * ko stays lane-uniform in VGPRs from LDS uint4 reads (no readfirstlane,
//    no SGPR arrays — R6/R7's scalar-ko SGPR pressure spilled to scratch).
//  * NO cross-phase prefetch, NO sched_barrier, plain __syncthreads
//    (R4/R6/R7 all spilled; R5's sync structure is the proven-clean base).
// ---------------------------------------------------------------------------
__global__ __launch_bounds__(512, 4) void fused_schnet_kernel(
    const int* __restrict__ z, const float* __restrict__ emb,
    const unsigned* __restrict__ koG,
    const float* __restrict__ Tt,
    const unsigned short* __restrict__ Wtall,
    const float* __restrict__ cf2_b, const float* __restrict__ lin_b,
    const float* __restrict__ out1_b, const float* __restrict__ out2_w,
    const float* __restrict__ out2_b,
    float* __restrict__ out)
{
    __shared__ float s_h[32 * STRH];                 // 16.9 KB fp32 node state
    __shared__ float s_hx[32 * 128];                 // 16.4 KB fp32
    __shared__ unsigned short s_agg[32 * STRA];      //  8.7 KB bf16
    __shared__ unsigned int s_ko[32 * 32];           //  4.0 KB pair knot offsets
    __shared__ float s_red;
    unsigned short* s_t = (unsigned short*)s_hx;     // [32][STRA] alias (8.7KB)

    const int tid  = threadIdx.x;
    const int lane = tid & 63;
    const int w    = tid >> 6;          // wave 0..7
    const int l15  = lane & 15;
    const int quad = lane >> 4;
    const int r16  = (w & 1) * 16;      // GEMM row tile
    const int c32  = (w >> 1) * 32;     // GEMM col tile
    const int B0   = blockIdx.x * 32;   // molecule base atom

    const unsigned lOff = (unsigned)(lane << 3);     // 8B into fp32 table row (2 ch)

    // init h; stage dense knot table (once — constant across layers)
    for (int i = tid; i < 32 * 128; i += 512) {
        int row = i >> 7, col = i & 127;
        s_h[row * STRH + col] = emb[(size_t)z[B0 + row] * 128 + col];
    }
    for (int i = tid; i < 1024; i += 512)
        s_ko[i] = koG[((size_t)blockIdx.x << 10) + i];
    if (tid == 0) s_red = 0.0f;

    __syncthreads();   // s_h / s_ko ready

    const unsigned short* WtO = Wtall + 9 * 16384;   // out1^T

    for (int l = 0; l < 3; l++) {
        const unsigned short* W1 = Wtall + (size_t)(l * 3 + 0) * 16384;
        const unsigned short* W2 = Wtall + (size_t)(l * 3 + 1) * 16384;
        const unsigned short* W3 = Wtall + (size_t)(l * 3 + 2) * 16384;
        const char* TlB = (const char*)(Tt + (size_t)l * (KTAB + 1) * 128);

        // ---- GEMM1: hx = h @ cf1 (16x32 tile per wave) ----
        floatx4 acc[2];
        #pragma unroll
        for (int nt = 0; nt < 2; nt++) acc[nt] = (floatx4){0.f, 0.f, 0.f, 0.f};
        #pragma unroll
        for (int ks = 0; ks < 4; ks++) {
            const float* hp = &s_h[(r16 + l15) * STRH + ks * 32 + quad * 8];
            float4 xa = *(const float4*)hp;
            float4 xb = *(const float4*)(hp + 4);
            unsigned int ap[4];
            ap[0] = pk2bf(xa.x, xa.y); ap[1] = pk2bf(xa.z, xa.w);
            ap[2] = pk2bf(xb.x, xb.y); ap[3] = pk2bf(xb.z, xb.w);
            short8 af;
            __builtin_memcpy(&af, ap, 16);
            #pragma unroll
            for (int nt = 0; nt < 2; nt++) {
                short8 bfg = *(const short8*)&W1[(size_t)(c32 + nt * 16 + l15) * 128 + ks * 32 + quad * 8];
                acc[nt] = __builtin_amdgcn_mfma_f32_16x16x32_bf16(af, bfg, acc[nt], 0, 0, 0);
            }
        }
        #pragma unroll
        for (int nt = 0; nt < 2; nt++) {
            #pragma unroll
            for (int r = 0; r < 4; r++)
                s_hx[(r16 + quad * 4 + r) * 128 + c32 + nt * 16 + l15] = acc[nt][r];
        }

        __syncthreads();   // hx complete before gather reads

        // ---- gather: dense pairs; fp32 table rows + v_pk_fma_f32 ----
        {
            floatx2 av[4];
            #pragma unroll
            for (int i = 0; i < 4; i++) av[i] = (floatx2){0.f, 0.f};

            #pragma unroll
            for (int sc = 0; sc < 4; sc++) {
                unsigned ko[4][8];
                #pragma unroll
                for (int i = 0; i < 4; i++) {
                    uint4 ka = *(const uint4*)&s_ko[(((w << 2) + i) << 5) + (sc << 3)];
                    uint4 kb = *(const uint4*)&s_ko[(((w << 2) + i) << 5) + (sc << 3) + 4];
                    ko[i][0] = ka.x; ko[i][1] = ka.y; ko[i][2] = ka.z; ko[i][3] = ka.w;
                    ko[i][4] = kb.x; ko[i][5] = kb.y; ko[i][6] = kb.z; ko[i][7] = kb.w;
                }
                #pragma unroll
                for (int j = 0; j < 8; j++) {
                    floatx2 hv = *(const floatx2*)&s_hx[(((sc << 3) + j) << 7) + (lane << 1)];
                    #pragma unroll
                    for (int i = 0; i < 4; i++) {
                        floatx2 tp = *(const floatx2*)(TlB + (ko[i][j] + lOff));
                        av[i] = __builtin_elementwise_fma(tp, hv, av[i]);
                    }
                }
            }
            #pragma unroll
            for (int i = 0; i < 4; i++)
                *(unsigned*)&s_agg[((w << 2) + i) * STRA + (lane << 1)] = pk2bf(av[i].x, av[i].y);
        }

        __syncthreads();   // agg complete; hx reads done (s_t alias safe)

        // ---- GEMM2: t = ssp(agg @ cf2 + b) ----
        float bva[2], bvb[2];
        #pragma unroll
        for (int nt = 0; nt < 2; nt++) {
            bva[nt] = cf2_b[l * 128 + c32 + nt * 16 + l15];
            bvb[nt] = lin_b[l * 128 + c32 + nt * 16 + l15];
        }
        #pragma unroll
        for (int nt = 0; nt < 2; nt++) acc[nt] = (floatx4){0.f, 0.f, 0.f, 0.f};
        #pragma unroll
        for (int ks = 0; ks < 4; ks++) {
            short8 af = *(const short8*)&s_agg[(r16 + l15) * STRA + ks * 32 + quad * 8];
            #pragma unroll
            for (int nt = 0; nt < 2; nt++) {
                short8 bfg = *(const short8*)&W2[(size_t)(c32 + nt * 16 + l15) * 128 + ks * 32 + quad * 8];
                acc[nt] = __builtin_amdgcn_mfma_f32_16x16x32_bf16(af, bfg, acc[nt], 0, 0, 0);
            }
        }
        #pragma unroll
        for (int nt = 0; nt < 2; nt++) {
            #pragma unroll
            for (int r = 0; r < 4; r++) {
                int row = r16 + quad * 4 + r;
                s_t[row * STRA + c32 + nt * 16 + l15] = f2bf(ssp(acc[nt][r] + bva[nt]));
            }
        }

        __syncthreads();   // t complete (cross-wave cols needed by GEMM3)

        // ---- GEMM3: h += t @ lin + b ----
        #pragma unroll
        for (int nt = 0; nt < 2; nt++) acc[nt] = (floatx4){0.f, 0.f, 0.f, 0.f};
        #pragma unroll
        for (int ks = 0; ks < 4; ks++) {
            short8 af = *(const short8*)&s_t[(r16 + l15) * STRA + ks * 32 + quad * 8];
            #pragma unroll
            for (int nt = 0; nt < 2; nt++) {
                short8 bfg = *(const short8*)&W3[(size_t)(c32 + nt * 16 + l15) * 128 + ks * 32 + quad * 8];
                acc[nt] = __builtin_amdgcn_mfma_f32_16x16x32_bf16(af, bfg, acc[nt], 0, 0, 0);
            }
        }
        #pragma unroll
        for (int nt = 0; nt < 2; nt++) {
            #pragma unroll
            for (int r = 0; r < 4; r++) {
                int row = r16 + quad * 4 + r;
                s_h[row * STRH + c32 + nt * 16 + l15] += acc[nt][r] + bvb[nt];
            }
        }
        __syncthreads();   // h updates visible before next layer / head
    }

    // ---- head: out = sum_a ssp(h@out1 + b1)@out2 + 32*b2 ----
    const int c16 = (w >> 1) * 16;   // out1: 64 cols = 4 col tiles x 2 row tiles
    floatx4 ha = (floatx4){0.f, 0.f, 0.f, 0.f};
    #pragma unroll
    for (int ks = 0; ks < 4; ks++) {
        const float* hp = &s_h[(r16 + l15) * STRH + ks * 32 + quad * 8];
        float4 xa = *(const float4*)hp;
        float4 xb = *(const float4*)(hp + 4);
        unsigned int ap[4];
        ap[0] = pk2bf(xa.x, xa.y); ap[1] = pk2bf(xa.z, xa.w);
        ap[2] = pk2bf(xb.x, xb.y); ap[3] = pk2bf(xb.z, xb.w);
        short8 af;
        __builtin_memcpy(&af, ap, 16);
        short8 bfg = *(const short8*)&WtO[(size_t)(c16 + l15) * 128 + ks * 32 + quad * 8];
        ha = __builtin_amdgcn_mfma_f32_16x16x32_bf16(af, bfg, ha, 0, 0, 0);
    }
    float part = 0.0f;
    {
        float b1o = out1_b[c16 + l15];
        float o2  = out2_w[c16 + l15];
        #pragma unroll
        for (int r = 0; r < 4; r++)
            part += ssp(ha[r] + b1o) * o2;
    }
    #pragma unroll
    for (int off = 32; off > 0; off >>= 1) part += __shfl_down(part, off);
    if (lane == 0) atomicAdd(&s_red, part);
    __syncthreads();
    if (tid == 0) out[blockIdx.x] = s_red + 32.0f * out2_b[0];
}

extern "C" void kernel_launch(void* const* d_in, const int* in_sizes, int n_in,
                              void* d_out, int out_size, void* d_ws, size_t ws_size,
                              hipStream_t stream)
{
    const int*   z      = (const int*)d_in[0];
    const float* pos    = (const float*)d_in[1];
    const float* emb    = (const float*)d_in[4];
    const float* mlp_w1 = (const float*)d_in[5];
    const float* mlp_b1 = (const float*)d_in[6];
    const float* mlp_w2 = (const float*)d_in[7];
    const float* mlp_b2 = (const float*)d_in[8];
    const float* cf1_w  = (const float*)d_in[9];
    const float* cf2_w  = (const float*)d_in[10];
    const float* cf2_b  = (const float*)d_in[11];
    const float* lin_w  = (const float*)d_in[12];
    const float* lin_b  = (const float*)d_in[13];
    const float* out1_w = (const float*)d_in[14];
    const float* out1_b = (const float*)d_in[15];
    const float* out2_w = (const float*)d_in[16];
    const float* out2_b = (const float*)d_in[17];

    // workspace carve-up (16B-aligned sections)
    char* p = (char*)d_ws;
    unsigned* koG = (unsigned*)p;                 p += (size_t)NMOL * 1024 * 4;       // 2.0 MB
    float* Tt = (float*)p;                        p += (size_t)3 * (KTAB + 1) * 128 * 4;  // 6.3 MB
    unsigned short* Wtall = (unsigned short*)p;   // 9*16384 + 64*128 ushorts

    const int WB = (9 * 16384 + 64 * 128 + 255) / 256;
    const int TB = NTILE * 3;
    mega_setup_kernel<<<NMOL + WB + TB, 256, 0, stream>>>(
        pos, koG, cf1_w, cf2_w, lin_w, out1_w, Wtall,
        mlp_w1, mlp_b1, mlp_w2, mlp_b2, Tt);

    fused_schnet_kernel<<<NMOL, 512, 0, stream>>>(
        z, emb, koG, Tt, Wtall,
        cf2_b, lin_b, out1_b, out2_w, out2_b, (float*)d_out);
}

// Round 9
// 159.269 us; speedup vs baseline: 2.4240x; 1.1833x over previous
//
#include <hip/hip_runtime.h>
#include <hip/hip_bf16.h>
#include <hip/hip_fp16.h>
#include <math.h>

// Problem constants (SchNet reference)
#define NATOMS 16384
#define NMOL   512
#define APM    32
#define GDIM   50
#define KTAB   4096   // filter lookup-table knots over d in [0,6] (nearest-knot)

#define STRH 132      // s_h row stride (floats), 528B
#define STRA 136      // s_agg / s_t row stride (ushorts), 272B

typedef __attribute__((ext_vector_type(8))) short   short8;   // 8 bf16 (A/B frag)
typedef __attribute__((ext_vector_type(4))) float   floatx4;  // C/D frag

// fast shifted softplus: log(1+exp(x)) - log2, via HW v_exp_f32/v_log_f32
__device__ __forceinline__ float ssp(float x) {
    float e = __expf(-fabsf(x));
    return fmaxf(x, 0.0f) + __logf(1.0f + e) - 0.69314718055994531f;
}

__device__ __forceinline__ unsigned short f2bf(float x) {
    union { float f; unsigned int u; } v; v.f = x;
    unsigned int lsb = (v.u >> 16) & 1u;
    v.u += 0x7fffu + lsb;
    return (unsigned short)(v.u >> 16);
}

__device__ __forceinline__ unsigned short f2h(float x) {
    __half h = __float2half(x);          // round-to-nearest
    unsigned short u;
    __builtin_memcpy(&u, &h, 2);
    return u;
}

__device__ __forceinline__ unsigned int pk2bf(float a, float b) {
    __hip_bfloat162 h = __float22bfloat162_rn(make_float2(a, b));
    unsigned int u;
    __builtin_memcpy(&u, &h, 4);
    return u;
}

// ---------------------------------------------------------------------------
// MEGA-SETUP (single dispatch, 3 block regions):
//  [0,NMOL):       dense pair-knot table koG[mol][dst][src] (byte offsets,
//                  k<<8 into 256B f16 rows; sentinel = zero-row) computed
//                  straight from positions. Blocks 0..2 zero sentinel rows.
//  [NMOL,+WB):     weights fp32 -> bf16 B-frag transpose (9x128x128 + out1)
//  [NMOL+WB,+192): filter table, 64 tiles x 3 layers, F16 rows (R9: f16 so
//                  the gather consumes halves directly via v_fma_mix_f32 —
//                  no unpack; f16 is also MORE precise than bf16 here):
//                  T[l][k][f] = ((ssp(ea(d_k)@w1+b1)@w2)+b2)*cut(d_k)
//  Each layer has KTAB+1 rows; row KTAB is all-zero (dense-gather sentinel).
// ---------------------------------------------------------------------------
#define KW1 72
#define KW2 136
#define NTILE (KTAB / 64)   // 64 tiles per layer

__global__ __launch_bounds__(256) void mega_setup_kernel(
    const float* __restrict__ pos,
    unsigned* __restrict__ koG,
    const float* __restrict__ cf1, const float* __restrict__ cf2,
    const float* __restrict__ lin, const float* __restrict__ out1,
    unsigned short* __restrict__ Wtall,
    const float* __restrict__ w1_, const float* __restrict__ b1_,
    const float* __restrict__ w2_, const float* __restrict__ b2_,
    unsigned short* __restrict__ Tt)
{
    const int WB = (9 * 16384 + 64 * 128 + 255) / 256;
    const int b = blockIdx.x;
    const int tid = threadIdx.x;

    __shared__ float sp[96];

    if (b < NMOL) {
        // ---- dense koG for molecule b ----
        if (tid < 96) sp[tid] = pos[b * 96 + tid];
        if (b < 3 && tid < 128)
            Tt[(size_t)b * (KTAB + 1) * 128 + (size_t)KTAB * 128 + tid] = 0;  // zero row
        __syncthreads();
        #pragma unroll
        for (int c4 = 0; c4 < 4; c4++) {
            int c = c4 * 256 + tid;
            int i = c >> 5, j = c & 31;          // dst i, src j
            float dx = sp[3 * i]     - sp[3 * j];
            float dy = sp[3 * i + 1] - sp[3 * j + 1];
            float dz = sp[3 * i + 2] - sp[3 * j + 2];
            float d  = sqrtf(dx * dx + dy * dy + dz * dz);
            unsigned off = (unsigned)(KTAB << 8);      // sentinel: zero row
            if (i != j && d <= 6.0f) {
                float u = d * (float)(KTAB - 1) / 6.0f;
                int k = min((int)(u + 0.5f), KTAB - 1);
                off = (unsigned)(k << 8);
            }
            koG[((size_t)b << 10) + c] = off;
        }
        return;
    }
    if (b < NMOL + WB) {
        int idx = (b - NMOL) * 256 + tid;
        if (idx < 9 * 16384) {
            int wi = idx >> 14, rem = idx & 16383;
            int n = rem >> 7, k = rem & 127;
            int l = wi / 3, which = wi % 3;
            const float* src = (which == 0) ? cf1 : (which == 1) ? cf2 : lin;
            Wtall[idx] = f2bf(src[(size_t)l * 16384 + k * 128 + n]);
        } else if (idx < 9 * 16384 + 64 * 128) {
            int q = idx - 9 * 16384;
            int n = q >> 7, k = q & 127;
            Wtall[idx] = f2bf(out1[k * 64 + n]);
        }
        return;
    }

    // ---------------- table region: tt = (layer, tile) ----------------
    __shared__ unsigned short s_bufA[128 * KW2];   // w2T
    __shared__ unsigned short s_bufB[128 * KW1];   // w1T, then s_t (alias)

    const int tt = b - NMOL - WB;
    const int l  = tt / NTILE;
    const int bx = tt % NTILE;
    const float* w1 = w1_ + (size_t)l * GDIM * 128;
    const float* b1 = b1_ + (size_t)l * 128;
    const float* w2 = w2_ + (size_t)l * 128 * 128;
    const float* b2 = b2_ + (size_t)l * 128;
    unsigned short* Tg = Tt + (size_t)l * (KTAB + 1) * 128;

    unsigned short* s_w1T = s_bufB;                // [128][KW1]
    unsigned short* s_w2T = s_bufA;                // [128][KW2]
    unsigned short* s_t   = s_bufB;                // [64][KW2] (after barrier)

    for (int i = tid; i < GDIM * 128; i += 256) {
        int g = i >> 7, f = i & 127;
        s_w1T[f * KW1 + g] = f2bf(w1[i]);
    }
    for (int i = tid; i < (64 - GDIM) * 128; i += 256) {
        int g = GDIM + (i >> 7), f = i & 127;
        s_w1T[f * KW1 + g] = 0;
    }
    for (int i = tid; i < 128 * 128; i += 256) {
        int k = i >> 7, n = i & 127;
        s_w2T[n * KW2 + k] = f2bf(w2[i]);
    }

    const int lane = tid & 63;
    const int w    = tid >> 6;
    const int l15  = lane & 15;
    const int quad = lane >> 4;

    float b1v[8], b2v[8];
    #pragma unroll
    for (int nt = 0; nt < 8; nt++) {
        b1v[nt] = b1[nt * 16 + l15];
        b2v[nt] = b2[nt * 16 + l15];
    }
    __syncthreads();

    const float hstep = 6.0f / (float)(KTAB - 1);
    const float step  = 6.0f / 49.0f;
    const float coeff = -0.5f / (step * step);
    const float pioc  = 3.14159265358979323846f / 6.0f;
    const int k0 = bx * 64;
    const float dm = (float)(k0 + w * 16 + l15) * hstep;

    floatx4 acc1[8];
    #pragma unroll
    for (int nt = 0; nt < 8; nt++) acc1[nt] = (floatx4){0.f, 0.f, 0.f, 0.f};
    #pragma unroll
    for (int ks = 0; ks < 2; ks++) {
        unsigned int ap[4];
        #pragma unroll
        for (int jj = 0; jj < 4; jj++) {
            int g0 = ks * 32 + quad * 8 + 2 * jj;
            float d0 = dm - (float)g0 * step;
            float d1 = dm - (float)(g0 + 1) * step;
            float v0 = (g0 < GDIM)     ? __expf(coeff * d0 * d0) : 0.0f;
            float v1 = (g0 + 1 < GDIM) ? __expf(coeff * d1 * d1) : 0.0f;
            ap[jj] = pk2bf(v0, v1);
        }
        short8 af;
        __builtin_memcpy(&af, ap, 16);
        #pragma unroll
        for (int nt = 0; nt < 8; nt++) {
            short8 bfg = *(const short8*)&s_w1T[(nt * 16 + l15) * KW1 + ks * 32 + quad * 8];
            acc1[nt] = __builtin_amdgcn_mfma_f32_16x16x32_bf16(af, bfg, acc1[nt], 0, 0, 0);
        }
    }
    __syncthreads();   // all waves done reading s_w1T; s_t may alias it

    #pragma unroll
    for (int nt = 0; nt < 8; nt++) {
        #pragma unroll
        for (int r = 0; r < 4; r++) {
            int row = w * 16 + quad * 4 + r;
            s_t[row * KW2 + nt * 16 + l15] = f2bf(ssp(acc1[nt][r] + b1v[nt]));
        }
    }
    // no barrier: wave reads only rows it wrote

    floatx4 acc2[8];
    #pragma unroll
    for (int nt = 0; nt < 8; nt++) acc2[nt] = (floatx4){0.f, 0.f, 0.f, 0.f};
    #pragma unroll
    for (int ks = 0; ks < 4; ks++) {
        short8 af = *(const short8*)&s_t[(w * 16 + l15) * KW2 + ks * 32 + quad * 8];
        #pragma unroll
        for (int nt = 0; nt < 8; nt++) {
            short8 bfg = *(const short8*)&s_w2T[(nt * 16 + l15) * KW2 + ks * 32 + quad * 8];
            acc2[nt] = __builtin_amdgcn_mfma_f32_16x16x32_bf16(af, bfg, acc2[nt], 0, 0, 0);
        }
    }

    #pragma unroll
    for (int nt = 0; nt < 8; nt++) {
        #pragma unroll
        for (int r = 0; r < 4; r++) {
            int row = w * 16 + quad * 4 + r;
            float d = (float)(k0 + row) * hstep;
            float cut = 0.5f * (__cosf(d * pioc) + 1.0f);
            Tg[(size_t)(k0 + row) * 128 + nt * 16 + l15] = f2h((acc2[nt][r] + b2v[nt]) * cut);
        }
    }
}

// ---------------------------------------------------------------------------
// Fully-fused SchNet: one block = one molecule, 512 threads = 8 waves.
// GEMM tile per wave: rows (w&1)*16, cols (w>>1)*32.
// Gather (R17 = R5 skeleton + f16 table + v_fma_mix_f32):
//  * table rows are f16 (same 256B rows, same k<<8 offsets, same dword
//    loads via rfl->saddr as the proven 61.5us R5 shape).
//  * per pair per lane: 2x v_fma_mix_f32 (op_sel picks lo/hi f16 half of
//    the loaded uint, f32 accumulate) replaces 2 unpack + 2 fma -> gather
//    VALU cut ~27% with ZERO change to loads/LDS/sync/registers.
//  * NO cross-phase prefetch, NO sched_barrier, plain __syncthreads
//    (R4/R6/R7 spilled; R8's fp32 table doubled L2 payload and regressed).
// ---------------------------------------------------------------------------
__global__ __launch_bounds__(512, 4) void fused_schnet_kernel(
    const int* __restrict__ z, const float* __restrict__ emb,
    const unsigned* __restrict__ koG,
    const unsigned short* __restrict__ Tt,
    const unsigned short* __restrict__ Wtall,
    const float* __restrict__ cf2_b, const float* __restrict__ lin_b,
    const float* __restrict__ out1_b, const float* __restrict__ out2_w,
    const float* __restrict__ out2_b,
    float* __restrict__ out)
{
    __shared__ float s_h[32 * STRH];                 // 16.9 KB fp32 node state
    __shared__ float s_hx[32 * 128];                 // 16.4 KB fp32
    __shared__ unsigned short s_agg[32 * STRA];      //  8.7 KB bf16
    __shared__ unsigned int s_ko[32 * 32];           //  4.0 KB pair knot offsets
    __shared__ float s_red;
    unsigned short* s_t = (unsigned short*)s_hx;     // [32][STRA] alias (8.7KB)

    const int tid  = threadIdx.x;
    const int lane = tid & 63;
    const int w    = tid >> 6;          // wave 0..7
    const int l15  = lane & 15;
    const int quad = lane >> 4;
    const int r16  = (w & 1) * 16;      // GEMM row tile
    const int c32  = (w >> 1) * 32;     // GEMM col tile
    const int B0   = blockIdx.x * 32;   // molecule base atom

    const unsigned lOff = (unsigned)(lane << 2);     // 4B into table row (2 f16)

    // init h; stage dense knot table (once — constant across layers)
    for (int i = tid; i < 32 * 128; i += 512) {
        int row = i >> 7, col = i & 127;
        s_h[row * STRH + col] = emb[(size_t)z[B0 + row] * 128 + col];
    }
    for (int i = tid; i < 1024; i += 512)
        s_ko[i] = koG[((size_t)blockIdx.x << 10) + i];
    if (tid == 0) s_red = 0.0f;

    __syncthreads();   // s_h / s_ko ready

    const unsigned short* WtO = Wtall + 9 * 16384;   // out1^T

#define KO_RFL(KO, SC)                                                        \
    _Pragma("unroll")                                                         \
    for (int i = 0; i < 4; i++) {                                             \
        uint4 ka = *(const uint4*)&s_ko[(((w << 2) + i) << 5) + ((SC) << 3)]; \
        uint4 kb = *(const uint4*)&s_ko[(((w << 2) + i) << 5) + ((SC) << 3) + 4]; \
        KO[i][0] = __builtin_amdgcn_readfirstlane(ka.x);                      \
        KO[i][1] = __builtin_amdgcn_readfirstlane(ka.y);                      \
        KO[i][2] = __builtin_amdgcn_readfirstlane(ka.z);                      \
        KO[i][3] = __builtin_amdgcn_readfirstlane(ka.w);                      \
        KO[i][4] = __builtin_amdgcn_readfirstlane(kb.x);                      \
        KO[i][5] = __builtin_amdgcn_readfirstlane(kb.y);                      \
        KO[i][6] = __builtin_amdgcn_readfirstlane(kb.z);                      \
        KO[i][7] = __builtin_amdgcn_readfirstlane(kb.w);                      \
    }
#define TP_LOAD(TP, KO)                                                       \
    _Pragma("unroll")                                                         \
    for (int i = 0; i < 4; i++) {                                             \
        _Pragma("unroll")                                                     \
        for (int j = 0; j < 8; j++)                                           \
            TP[i][j] = *(const unsigned*)(TlB + KO[i][j] + lOff);             \
    }
#define FMA_CHUNK(TP, SC)                                                     \
    _Pragma("unroll")                                                         \
    for (int j = 0; j < 8; j++) {                                             \
        float2 hv = *(const float2*)&s_hx[((((SC) << 3) + j) << 7) + (lane << 1)]; \
        _Pragma("unroll")                                                     \
        for (int i = 0; i < 4; i++) {                                         \
            unsigned t = TP[i][j];                                            \
            asm("v_fma_mix_f32 %0, %1, %2, %0 op_sel:[0,0,0] op_sel_hi:[1,0,0]" \
                : "+v"(a0[i]) : "v"(t), "v"(hv.x));                           \
            asm("v_fma_mix_f32 %0, %1, %2, %0 op_sel:[1,0,0] op_sel_hi:[1,0,0]" \
                : "+v"(a1[i]) : "v"(t), "v"(hv.y));                           \
        }                                                                     \
    }

    for (int l = 0; l < 3; l++) {
        const unsigned short* W1 = Wtall + (size_t)(l * 3 + 0) * 16384;
        const unsigned short* W2 = Wtall + (size_t)(l * 3 + 1) * 16384;
        const unsigned short* W3 = Wtall + (size_t)(l * 3 + 2) * 16384;
        const char* TlB = (const char*)(Tt + (size_t)l * (KTAB + 1) * 128);

        // ---- GEMM1: hx = h @ cf1 (16x32 tile per wave) ----
        floatx4 acc[2];
        #pragma unroll
        for (int nt = 0; nt < 2; nt++) acc[nt] = (floatx4){0.f, 0.f, 0.f, 0.f};
        #pragma unroll
        for (int ks = 0; ks < 4; ks++) {
            const float* hp = &s_h[(r16 + l15) * STRH + ks * 32 + quad * 8];
            float4 xa = *(const float4*)hp;
            float4 xb = *(const float4*)(hp + 4);
            unsigned int ap[4];
            ap[0] = pk2bf(xa.x, xa.y); ap[1] = pk2bf(xa.z, xa.w);
            ap[2] = pk2bf(xb.x, xb.y); ap[3] = pk2bf(xb.z, xb.w);
            short8 af;
            __builtin_memcpy(&af, ap, 16);
            #pragma unroll
            for (int nt = 0; nt < 2; nt++) {
                short8 bfg = *(const short8*)&W1[(size_t)(c32 + nt * 16 + l15) * 128 + ks * 32 + quad * 8];
                acc[nt] = __builtin_amdgcn_mfma_f32_16x16x32_bf16(af, bfg, acc[nt], 0, 0, 0);
            }
        }
        #pragma unroll
        for (int nt = 0; nt < 2; nt++) {
            #pragma unroll
            for (int r = 0; r < 4; r++)
                s_hx[(r16 + quad * 4 + r) * 128 + c32 + nt * 16 + l15] = acc[nt][r];
        }

        __syncthreads();   // hx complete before gather reads

        // ---- gather: dense pairs, 2-buffer chunks (R5 structure) ----
        {
            float a0[4], a1[4];
            #pragma unroll
            for (int i = 0; i < 4; i++) { a0[i] = 0.0f; a1[i] = 0.0f; }

            unsigned koA[4][8], koB[4][8], tpA[4][8], tpB[4][8];
            KO_RFL(koA, 0)
            TP_LOAD(tpA, koA)

            KO_RFL(koB, 1)
            TP_LOAD(tpB, koB)
            FMA_CHUNK(tpA, 0)

            KO_RFL(koA, 2)
            TP_LOAD(tpA, koA)
            FMA_CHUNK(tpB, 1)

            KO_RFL(koB, 3)
            TP_LOAD(tpB, koB)
            FMA_CHUNK(tpA, 2)

            FMA_CHUNK(tpB, 3)

            #pragma unroll
            for (int i = 0; i < 4; i++)
                *(unsigned*)&s_agg[((w << 2) + i) * STRA + (lane << 1)] = pk2bf(a0[i], a1[i]);
        }

        __syncthreads();   // agg complete; hx reads done (s_t alias safe)

        // ---- GEMM2: t = ssp(agg @ cf2 + b) ----
        float bva[2], bvb[2];
        #pragma unroll
        for (int nt = 0; nt < 2; nt++) {
            bva[nt] = cf2_b[l * 128 + c32 + nt * 16 + l15];
            bvb[nt] = lin_b[l * 128 + c32 + nt * 16 + l15];
        }
        #pragma unroll
        for (int nt = 0; nt < 2; nt++) acc[nt] = (floatx4){0.f, 0.f, 0.f, 0.f};
        #pragma unroll
        for (int ks = 0; ks < 4; ks++) {
            short8 af = *(const short8*)&s_agg[(r16 + l15) * STRA + ks * 32 + quad * 8];
            #pragma unroll
            for (int nt = 0; nt < 2; nt++) {
                short8 bfg = *(const short8*)&W2[(size_t)(c32 + nt * 16 + l15) * 128 + ks * 32 + quad * 8];
                acc[nt] = __builtin_amdgcn_mfma_f32_16x16x32_bf16(af, bfg, acc[nt], 0, 0, 0);
            }
        }
        #pragma unroll
        for (int nt = 0; nt < 2; nt++) {
            #pragma unroll
            for (int r = 0; r < 4; r++) {
                int row = r16 + quad * 4 + r;
                s_t[row * STRA + c32 + nt * 16 + l15] = f2bf(ssp(acc[nt][r] + bva[nt]));
            }
        }

        __syncthreads();   // t complete (cross-wave cols needed by GEMM3)

        // ---- GEMM3: h += t @ lin + b ----
        #pragma unroll
        for (int nt = 0; nt < 2; nt++) acc[nt] = (floatx4){0.f, 0.f, 0.f, 0.f};
        #pragma unroll
        for (int ks = 0; ks < 4; ks++) {
            short8 af = *(const short8*)&s_t[(r16 + l15) * STRA + ks * 32 + quad * 8];
            #pragma unroll
            for (int nt = 0; nt < 2; nt++) {
                short8 bfg = *(const short8*)&W3[(size_t)(c32 + nt * 16 + l15) * 128 + ks * 32 + quad * 8];
                acc[nt] = __builtin_amdgcn_mfma_f32_16x16x32_bf16(af, bfg, acc[nt], 0, 0, 0);
            }
        }
        #pragma unroll
        for (int nt = 0; nt < 2; nt++) {
            #pragma unroll
            for (int r = 0; r < 4; r++) {
                int row = r16 + quad * 4 + r;
                s_h[row * STRH + c32 + nt * 16 + l15] += acc[nt][r] + bvb[nt];
            }
        }
        __syncthreads();   // h updates visible before next layer / head
    }

    // ---- head: out = sum_a ssp(h@out1 + b1)@out2 + 32*b2 ----
    const int c16 = (w >> 1) * 16;   // out1: 64 cols = 4 col tiles x 2 row tiles
    floatx4 ha = (floatx4){0.f, 0.f, 0.f, 0.f};
    #pragma unroll
    for (int ks = 0; ks < 4; ks++) {
        const float* hp = &s_h[(r16 + l15) * STRH + ks * 32 + quad * 8];
        float4 xa = *(const float4*)hp;
        float4 xb = *(const float4*)(hp + 4);
        unsigned int ap[4];
        ap[0] = pk2bf(xa.x, xa.y); ap[1] = pk2bf(xa.z, xa.w);
        ap[2] = pk2bf(xb.x, xb.y); ap[3] = pk2bf(xb.z, xb.w);
        short8 af;
        __builtin_memcpy(&af, ap, 16);
        short8 bfg = *(const short8*)&WtO[(size_t)(c16 + l15) * 128 + ks * 32 + quad * 8];
        ha = __builtin_amdgcn_mfma_f32_16x16x32_bf16(af, bfg, ha, 0, 0, 0);
    }
    float part = 0.0f;
    {
        float b1o = out1_b[c16 + l15];
        float o2  = out2_w[c16 + l15];
        #pragma unroll
        for (int r = 0; r < 4; r++)
            part += ssp(ha[r] + b1o) * o2;
    }
    #pragma unroll
    for (int off = 32; off > 0; off >>= 1) part += __shfl_down(part, off);
    if (lane == 0) atomicAdd(&s_red, part);
    __syncthreads();
    if (tid == 0) out[blockIdx.x] = s_red + 32.0f * out2_b[0];

#undef KO_RFL
#undef TP_LOAD
#undef FMA_CHUNK
}

extern "C" void kernel_launch(void* const* d_in, const int* in_sizes, int n_in,
                              void* d_out, int out_size, void* d_ws, size_t ws_size,
                              hipStream_t stream)
{
    const int*   z      = (const int*)d_in[0];
    const float* pos    = (const float*)d_in[1];
    const float* emb    = (const float*)d_in[4];
    const float* mlp_w1 = (const float*)d_in[5];
    const float* mlp_b1 = (const float*)d_in[6];
    const float* mlp_w2 = (const float*)d_in[7];
    const float* mlp_b2 = (const float*)d_in[8];
    const float* cf1_w  = (const float*)d_in[9];
    const float* cf2_w  = (const float*)d_in[10];
    const float* cf2_b  = (const float*)d_in[11];
    const float* lin_w  = (const float*)d_in[12];
    const float* lin_b  = (const float*)d_in[13];
    const float* out1_w = (const float*)d_in[14];
    const float* out1_b = (const float*)d_in[15];
    const float* out2_w = (const float*)d_in[16];
    const float* out2_b = (const float*)d_in[17];

    // workspace carve-up (16B-aligned sections)
    char* p = (char*)d_ws;
    unsigned* koG = (unsigned*)p;                 p += (size_t)NMOL * 1024 * 4;       // 2.0 MB
    unsigned short* Tt = (unsigned short*)p;      p += (size_t)3 * (KTAB + 1) * 128 * 2;
    unsigned short* Wtall = (unsigned short*)p;   // 9*16384 + 64*128 ushorts

    const int WB = (9 * 16384 + 64 * 128 + 255) / 256;
    const int TB = NTILE * 3;
    mega_setup_kernel<<<NMOL + WB + TB, 256, 0, stream>>>(
        pos, koG, cf1_w, cf2_w, lin_w, out1_w, Wtall,
        mlp_w1, mlp_b1, mlp_w2, mlp_b2, Tt);

    fused_schnet_kernel<<<NMOL, 512, 0, stream>>>(
        z, emb, koG, Tt, Wtall,
        cf2_b, lin_b, out1_b, out2_w, out2_b, (float*)d_out);
}

// Round 10
// 156.354 us; speedup vs baseline: 2.4692x; 1.0186x over previous
//
#include <hip/hip_runtime.h>
#include <hip/hip_bf16.h>
#include <hip/hip_fp16.h>
#include <math.h>

// Problem constants (SchNet reference)
#define NATOMS 16384
#define NMOL   512
#define APM    32
#define GDIM   50
#define KTAB   4096   // filter lookup-table knots over d in [0,6] (nearest-knot)

#define STRH 132      // s_h row stride (floats), 528B
#define STRA 136      // s_agg / s_t row stride (ushorts), 272B

typedef __attribute__((ext_vector_type(8))) short   short8;   // 8 bf16 (A/B frag)
typedef __attribute__((ext_vector_type(4))) float   floatx4;  // C/D frag

// fast shifted softplus: log(1+exp(x)) - log2, via HW v_exp_f32/v_log_f32
__device__ __forceinline__ float ssp(float x) {
    float e = __expf(-fabsf(x));
    return fmaxf(x, 0.0f) + __logf(1.0f + e) - 0.69314718055994531f;
}

__device__ __forceinline__ unsigned short f2bf(float x) {
    union { float f; unsigned int u; } v; v.f = x;
    unsigned int lsb = (v.u >> 16) & 1u;
    v.u += 0x7fffu + lsb;
    return (unsigned short)(v.u >> 16);
}

__device__ __forceinline__ unsigned short f2h(float x) {
    __half h = __float2half(x);          // round-to-nearest
    unsigned short u;
    __builtin_memcpy(&u, &h, 2);
    return u;
}

__device__ __forceinline__ unsigned int pk2bf(float a, float b) {
    __hip_bfloat162 h = __float22bfloat162_rn(make_float2(a, b));
    unsigned int u;
    __builtin_memcpy(&u, &h, 4);
    return u;
}

#define KW2 136
#define NTILE (KTAB / 64)   // 64 tiles per layer

// WB region element counts (setup_a weight transposes)
#define N_WTALL  147456            // 9*16384 (cf1/cf2/lin transposed)
#define N_OUT1   8192              // out1 64x128
#define N_W1T    24576             // 3 layers x 128 n x 64 k (pad k>=50 with 0)
#define N_W2T    49152             // 3 layers x 128 n x 128 k
#define WB_ELEMS (N_WTALL + N_OUT1 + N_W1T + N_W2T)   // 229376
#define WB_BLOCKS (WB_ELEMS / 256)                     // 896

// ---------------------------------------------------------------------------
// SETUP-A (one dispatch, 2 block regions):
//  [0,NMOL):        dense pair-knot table koG[mol][dst][src] (byte offsets,
//                   k<<8 into 256B f16 rows; sentinel = zero-row) from
//                   positions. Blocks 0..2 also zero the Tt sentinel rows.
//  [NMOL,+896):     ALL weight transposes fp32 -> bf16 B-frag layout:
//                   Wtall (cf1/cf2/lin, out1) as before, PLUS Wmlp
//                   (mlp_w1 k-padded to 64, mlp_w2) — R10: pre-transposing
//                   mlp weights once removes the 22.8k-element LDS staging
//                   that EVERY table block repeated (64x redundant per layer).
// Table generation moved to setup_b (separate dispatch — table blocks read
// Wmlp written here; same-dispatch would be an intra-dispatch race).
// ---------------------------------------------------------------------------
__global__ __launch_bounds__(256) void setup_a_kernel(
    const float* __restrict__ pos,
    unsigned* __restrict__ koG,
    const float* __restrict__ cf1, const float* __restrict__ cf2,
    const float* __restrict__ lin, const float* __restrict__ out1,
    const float* __restrict__ w1_, const float* __restrict__ w2_,
    unsigned short* __restrict__ Wtall, unsigned short* __restrict__ Wmlp,
    unsigned short* __restrict__ Tt)
{
    const int b = blockIdx.x;
    const int tid = threadIdx.x;

    __shared__ float sp[96];

    if (b < NMOL) {
        // ---- dense koG for molecule b ----
        if (tid < 96) sp[tid] = pos[b * 96 + tid];
        if (b < 3 && tid < 128)
            Tt[(size_t)b * (KTAB + 1) * 128 + (size_t)KTAB * 128 + tid] = 0;  // zero row
        __syncthreads();
        #pragma unroll
        for (int c4 = 0; c4 < 4; c4++) {
            int c = c4 * 256 + tid;
            int i = c >> 5, j = c & 31;          // dst i, src j
            float dx = sp[3 * i]     - sp[3 * j];
            float dy = sp[3 * i + 1] - sp[3 * j + 1];
            float dz = sp[3 * i + 2] - sp[3 * j + 2];
            float d  = sqrtf(dx * dx + dy * dy + dz * dz);
            unsigned off = (unsigned)(KTAB << 8);      // sentinel: zero row
            if (i != j && d <= 6.0f) {
                float u = d * (float)(KTAB - 1) / 6.0f;
                int k = min((int)(u + 0.5f), KTAB - 1);
                off = (unsigned)(k << 8);
            }
            koG[((size_t)b << 10) + c] = off;
        }
        return;
    }

    int idx = (b - NMOL) * 256 + tid;
    if (idx < N_WTALL) {
        int wi = idx >> 14, rem = idx & 16383;
        int n = rem >> 7, k = rem & 127;
        int l = wi / 3, which = wi % 3;
        const float* src = (which == 0) ? cf1 : (which == 1) ? cf2 : lin;
        Wtall[idx] = f2bf(src[(size_t)l * 16384 + k * 128 + n]);
    } else if (idx < N_WTALL + N_OUT1) {
        int q = idx - N_WTALL;
        int n = q >> 7, k = q & 127;
        Wtall[idx] = f2bf(out1[k * 64 + n]);
    } else if (idx < N_WTALL + N_OUT1 + N_W1T) {
        int q = idx - (N_WTALL + N_OUT1);
        int l = q >> 13, rem = q & 8191;
        int n = rem >> 6, k = rem & 63;
        Wmlp[q] = (k < GDIM) ? f2bf(w1_[(size_t)l * GDIM * 128 + k * 128 + n]) : 0;
    } else {
        int q = idx - (N_WTALL + N_OUT1 + N_W1T);
        int l = q >> 14, rem = q & 16383;
        int n = rem >> 7, k = rem & 127;
        Wmlp[N_W1T + q] = f2bf(w2_[(size_t)l * 16384 + k * 128 + n]);
    }
}

// ---------------------------------------------------------------------------
// SETUP-B: filter table, 64 tiles x 3 layers, F16 rows:
//   T[l][k][f] = ((ssp(ea(d_k)@w1+b1)@w2)+b2)*cut(d_k)
// B-fragments loaded DIRECTLY from pre-transposed global Wmlp (16B short8,
// same pattern as the fused GEMMs) — no LDS weight staging, no barriers
// (s_t write->read is wave-local: each wave owns rows w*16..w*16+15).
// ---------------------------------------------------------------------------
__global__ __launch_bounds__(256) void setup_b_kernel(
    const unsigned short* __restrict__ Wmlp,
    const float* __restrict__ b1_, const float* __restrict__ b2_,
    unsigned short* __restrict__ Tt)
{
    __shared__ unsigned short s_t[64 * KW2];   // 17.4 KB intermediate

    const int tt = blockIdx.x;
    const int l  = tt / NTILE;
    const int bx = tt % NTILE;
    const unsigned short* W1g = Wmlp + (size_t)l * 8192;            // [n][64]
    const unsigned short* W2g = Wmlp + N_W1T + (size_t)l * 16384;   // [n][128]
    const float* b1 = b1_ + (size_t)l * 128;
    const float* b2 = b2_ + (size_t)l * 128;
    unsigned short* Tg = Tt + (size_t)l * (KTAB + 1) * 128;

    const int tid  = threadIdx.x;
    const int lane = tid & 63;
    const int w    = tid >> 6;          // wave 0..3, rows w*16..w*16+15
    const int l15  = lane & 15;
    const int quad = lane >> 4;

    float b1v[8], b2v[8];
    #pragma unroll
    for (int nt = 0; nt < 8; nt++) {
        b1v[nt] = b1[nt * 16 + l15];
        b2v[nt] = b2[nt * 16 + l15];
    }

    const float hstep = 6.0f / (float)(KTAB - 1);
    const float step  = 6.0f / 49.0f;
    const float coeff = -0.5f / (step * step);
    const float pioc  = 3.14159265358979323846f / 6.0f;
    const int k0 = bx * 64;
    const float dm = (float)(k0 + w * 16 + l15) * hstep;

    // ---- GEMM1: t1 = ea @ w1 (64 rows x 128, K=64 zero-padded) ----
    floatx4 acc1[8];
    #pragma unroll
    for (int nt = 0; nt < 8; nt++) acc1[nt] = (floatx4){0.f, 0.f, 0.f, 0.f};
    #pragma unroll
    for (int ks = 0; ks < 2; ks++) {
        unsigned int ap[4];
        #pragma unroll
        for (int jj = 0; jj < 4; jj++) {
            int g0 = ks * 32 + quad * 8 + 2 * jj;
            float d0 = dm - (float)g0 * step;
            float d1 = dm - (float)(g0 + 1) * step;
            float v0 = (g0 < GDIM)     ? __expf(coeff * d0 * d0) : 0.0f;
            float v1 = (g0 + 1 < GDIM) ? __expf(coeff * d1 * d1) : 0.0f;
            ap[jj] = pk2bf(v0, v1);
        }
        short8 af;
        __builtin_memcpy(&af, ap, 16);
        #pragma unroll
        for (int nt = 0; nt < 8; nt++) {
            short8 bfg = *(const short8*)&W1g[(nt * 16 + l15) * 64 + ks * 32 + quad * 8];
            acc1[nt] = __builtin_amdgcn_mfma_f32_16x16x32_bf16(af, bfg, acc1[nt], 0, 0, 0);
        }
    }

    // s_t write: wave-local rows; no barrier needed (same-wave LDS dep)
    #pragma unroll
    for (int nt = 0; nt < 8; nt++) {
        #pragma unroll
        for (int r = 0; r < 4; r++) {
            int row = w * 16 + quad * 4 + r;
            s_t[row * KW2 + nt * 16 + l15] = f2bf(ssp(acc1[nt][r] + b1v[nt]));
        }
    }

    // ---- GEMM2: t2 = ssp(t1) @ w2 ----
    floatx4 acc2[8];
    #pragma unroll
    for (int nt = 0; nt < 8; nt++) acc2[nt] = (floatx4){0.f, 0.f, 0.f, 0.f};
    #pragma unroll
    for (int ks = 0; ks < 4; ks++) {
        short8 af = *(const short8*)&s_t[(w * 16 + l15) * KW2 + ks * 32 + quad * 8];
        #pragma unroll
        for (int nt = 0; nt < 8; nt++) {
            short8 bfg = *(const short8*)&W2g[(nt * 16 + l15) * 128 + ks * 32 + quad * 8];
            acc2[nt] = __builtin_amdgcn_mfma_f32_16x16x32_bf16(af, bfg, acc2[nt], 0, 0, 0);
        }
    }

    #pragma unroll
    for (int nt = 0; nt < 8; nt++) {
        #pragma unroll
        for (int r = 0; r < 4; r++) {
            int row = w * 16 + quad * 4 + r;
            float d = (float)(k0 + row) * hstep;
            float cut = 0.5f * (__cosf(d * pioc) + 1.0f);
            Tg[(size_t)(k0 + row) * 128 + nt * 16 + l15] = f2h((acc2[nt][r] + b2v[nt]) * cut);
        }
    }
}

// ---------------------------------------------------------------------------
// Fully-fused SchNet: one block = one molecule, 512 threads = 8 waves.
// GEMM tile per wave: rows (w&1)*16, cols (w>>1)*32.
// Gather (R9 proven, 59.2us): R5 skeleton + f16 table + v_fma_mix_f32.
// UNCHANGED from R9 — setup restructuring only this round.
// ---------------------------------------------------------------------------
__global__ __launch_bounds__(512, 4) void fused_schnet_kernel(
    const int* __restrict__ z, const float* __restrict__ emb,
    const unsigned* __restrict__ koG,
    const unsigned short* __restrict__ Tt,
    const unsigned short* __restrict__ Wtall,
    const float* __restrict__ cf2_b, const float* __restrict__ lin_b,
    const float* __restrict__ out1_b, const float* __restrict__ out2_w,
    const float* __restrict__ out2_b,
    float* __restrict__ out)
{
    __shared__ float s_h[32 * STRH];                 // 16.9 KB fp32 node state
    __shared__ float s_hx[32 * 128];                 // 16.4 KB fp32
    __shared__ unsigned short s_agg[32 * STRA];      //  8.7 KB bf16
    __shared__ unsigned int s_ko[32 * 32];           //  4.0 KB pair knot offsets
    __shared__ float s_red;
    unsigned short* s_t = (unsigned short*)s_hx;     // [32][STRA] alias (8.7KB)

    const int tid  = threadIdx.x;
    const int lane = tid & 63;
    const int w    = tid >> 6;          // wave 0..7
    const int l15  = lane & 15;
    const int quad = lane >> 4;
    const int r16  = (w & 1) * 16;      // GEMM row tile
    const int c32  = (w >> 1) * 32;     // GEMM col tile
    const int B0   = blockIdx.x * 32;   // molecule base atom

    const unsigned lOff = (unsigned)(lane << 2);     // 4B into table row (2 f16)

    // init h; stage dense knot table (once — constant across layers)
    for (int i = tid; i < 32 * 128; i += 512) {
        int row = i >> 7, col = i & 127;
        s_h[row * STRH + col] = emb[(size_t)z[B0 + row] * 128 + col];
    }
    for (int i = tid; i < 1024; i += 512)
        s_ko[i] = koG[((size_t)blockIdx.x << 10) + i];
    if (tid == 0) s_red = 0.0f;

    __syncthreads();   // s_h / s_ko ready

    const unsigned short* WtO = Wtall + 9 * 16384;   // out1^T

#define KO_RFL(KO, SC)                                                        \
    _Pragma("unroll")                                                         \
    for (int i = 0; i < 4; i++) {                                             \
        uint4 ka = *(const uint4*)&s_ko[(((w << 2) + i) << 5) + ((SC) << 3)]; \
        uint4 kb = *(const uint4*)&s_ko[(((w << 2) + i) << 5) + ((SC) << 3) + 4]; \
        KO[i][0] = __builtin_amdgcn_readfirstlane(ka.x);                      \
        KO[i][1] = __builtin_amdgcn_readfirstlane(ka.y);                      \
        KO[i][2] = __builtin_amdgcn_readfirstlane(ka.z);                      \
        KO[i][3] = __builtin_amdgcn_readfirstlane(ka.w);                      \
        KO[i][4] = __builtin_amdgcn_readfirstlane(kb.x);                      \
        KO[i][5] = __builtin_amdgcn_readfirstlane(kb.y);                      \
        KO[i][6] = __builtin_amdgcn_readfirstlane(kb.z);                      \
        KO[i][7] = __builtin_amdgcn_readfirstlane(kb.w);                      \
    }
#define TP_LOAD(TP, KO)                                                       \
    _Pragma("unroll")                                                         \
    for (int i = 0; i < 4; i++) {                                             \
        _Pragma("unroll")                                                     \
        for (int j = 0; j < 8; j++)                                           \
            TP[i][j] = *(const unsigned*)(TlB + KO[i][j] + lOff);             \
    }
#define FMA_CHUNK(TP, SC)                                                     \
    _Pragma("unroll")                                                         \
    for (int j = 0; j < 8; j++) {                                             \
        float2 hv = *(const float2*)&s_hx[((((SC) << 3) + j) << 7) + (lane << 1)]; \
        _Pragma("unroll")                                                     \
        for (int i = 0; i < 4; i++) {                                         \
            unsigned t = TP[i][j];                                            \
            asm("v_fma_mix_f32 %0, %1, %2, %0 op_sel:[0,0,0] op_sel_hi:[1,0,0]" \
                : "+v"(a0[i]) : "v"(t), "v"(hv.x));                           \
            asm("v_fma_mix_f32 %0, %1, %2, %0 op_sel:[1,0,0] op_sel_hi:[1,0,0]" \
                : "+v"(a1[i]) : "v"(t), "v"(hv.y));                           \
        }                                                                     \
    }

    for (int l = 0; l < 3; l++) {
        const unsigned short* W1 = Wtall + (size_t)(l * 3 + 0) * 16384;
        const unsigned short* W2 = Wtall + (size_t)(l * 3 + 1) * 16384;
        const unsigned short* W3 = Wtall + (size_t)(l * 3 + 2) * 16384;
        const char* TlB = (const char*)(Tt + (size_t)l * (KTAB + 1) * 128);

        // ---- GEMM1: hx = h @ cf1 (16x32 tile per wave) ----
        floatx4 acc[2];
        #pragma unroll
        for (int nt = 0; nt < 2; nt++) acc[nt] = (floatx4){0.f, 0.f, 0.f, 0.f};
        #pragma unroll
        for (int ks = 0; ks < 4; ks++) {
            const float* hp = &s_h[(r16 + l15) * STRH + ks * 32 + quad * 8];
            float4 xa = *(const float4*)hp;
            float4 xb = *(const float4*)(hp + 4);
            unsigned int ap[4];
            ap[0] = pk2bf(xa.x, xa.y); ap[1] = pk2bf(xa.z, xa.w);
            ap[2] = pk2bf(xb.x, xb.y); ap[3] = pk2bf(xb.z, xb.w);
            short8 af;
            __builtin_memcpy(&af, ap, 16);
            #pragma unroll
            for (int nt = 0; nt < 2; nt++) {
                short8 bfg = *(const short8*)&W1[(size_t)(c32 + nt * 16 + l15) * 128 + ks * 32 + quad * 8];
                acc[nt] = __builtin_amdgcn_mfma_f32_16x16x32_bf16(af, bfg, acc[nt], 0, 0, 0);
            }
        }
        #pragma unroll
        for (int nt = 0; nt < 2; nt++) {
            #pragma unroll
            for (int r = 0; r < 4; r++)
                s_hx[(r16 + quad * 4 + r) * 128 + c32 + nt * 16 + l15] = acc[nt][r];
        }

        __syncthreads();   // hx complete before gather reads

        // ---- gather: dense pairs, 2-buffer chunks (R5 structure) ----
        {
            float a0[4], a1[4];
            #pragma unroll
            for (int i = 0; i < 4; i++) { a0[i] = 0.0f; a1[i] = 0.0f; }

            unsigned koA[4][8], koB[4][8], tpA[4][8], tpB[4][8];
            KO_RFL(koA, 0)
            TP_LOAD(tpA, koA)

            KO_RFL(koB, 1)
            TP_LOAD(tpB, koB)
            FMA_CHUNK(tpA, 0)

            KO_RFL(koA, 2)
            TP_LOAD(tpA, koA)
            FMA_CHUNK(tpB, 1)

            KO_RFL(koB, 3)
            TP_LOAD(tpB, koB)
            FMA_CHUNK(tpA, 2)

            FMA_CHUNK(tpB, 3)

            #pragma unroll
            for (int i = 0; i < 4; i++)
                *(unsigned*)&s_agg[((w << 2) + i) * STRA + (lane << 1)] = pk2bf(a0[i], a1[i]);
        }

        __syncthreads();   // agg complete; hx reads done (s_t alias safe)

        // ---- GEMM2: t = ssp(agg @ cf2 + b) ----
        float bva[2], bvb[2];
        #pragma unroll
        for (int nt = 0; nt < 2; nt++) {
            bva[nt] = cf2_b[l * 128 + c32 + nt * 16 + l15];
            bvb[nt] = lin_b[l * 128 + c32 + nt * 16 + l15];
        }
        #pragma unroll
        for (int nt = 0; nt < 2; nt++) acc[nt] = (floatx4){0.f, 0.f, 0.f, 0.f};
        #pragma unroll
        for (int ks = 0; ks < 4; ks++) {
            short8 af = *(const short8*)&s_agg[(r16 + l15) * STRA + ks * 32 + quad * 8];
            #pragma unroll
            for (int nt = 0; nt < 2; nt++) {
                short8 bfg = *(const short8*)&W2[(size_t)(c32 + nt * 16 + l15) * 128 + ks * 32 + quad * 8];
                acc[nt] = __builtin_amdgcn_mfma_f32_16x16x32_bf16(af, bfg, acc[nt], 0, 0, 0);
            }
        }
        #pragma unroll
        for (int nt = 0; nt < 2; nt++) {
            #pragma unroll
            for (int r = 0; r < 4; r++) {
                int row = r16 + quad * 4 + r;
                s_t[row * STRA + c32 + nt * 16 + l15] = f2bf(ssp(acc[nt][r] + bva[nt]));
            }
        }

        __syncthreads();   // t complete (cross-wave cols needed by GEMM3)

        // ---- GEMM3: h += t @ lin + b ----
        #pragma unroll
        for (int nt = 0; nt < 2; nt++) acc[nt] = (floatx4){0.f, 0.f, 0.f, 0.f};
        #pragma unroll
        for (int ks = 0; ks < 4; ks++) {
            short8 af = *(const short8*)&s_t[(r16 + l15) * STRA + ks * 32 + quad * 8];
            #pragma unroll
            for (int nt = 0; nt < 2; nt++) {
                short8 bfg = *(const short8*)&W3[(size_t)(c32 + nt * 16 + l15) * 128 + ks * 32 + quad * 8];
                acc[nt] = __builtin_amdgcn_mfma_f32_16x16x32_bf16(af, bfg, acc[nt], 0, 0, 0);
            }
        }
        #pragma unroll
        for (int nt = 0; nt < 2; nt++) {
            #pragma unroll
            for (int r = 0; r < 4; r++) {
                int row = r16 + quad * 4 + r;
                s_h[row * STRH + c32 + nt * 16 + l15] += acc[nt][r] + bvb[nt];
            }
        }
        __syncthreads();   // h updates visible before next layer / head
    }

    // ---- head: out = sum_a ssp(h@out1 + b1)@out2 + 32*b2 ----
    const int c16 = (w >> 1) * 16;   // out1: 64 cols = 4 col tiles x 2 row tiles
    floatx4 ha = (floatx4){0.f, 0.f, 0.f, 0.f};
    #pragma unroll
    for (int ks = 0; ks < 4; ks++) {
        const float* hp = &s_h[(r16 + l15) * STRH + ks * 32 + quad * 8];
        float4 xa = *(const float4*)hp;
        float4 xb = *(const float4*)(hp + 4);
        unsigned int ap[4];
        ap[0] = pk2bf(xa.x, xa.y); ap[1] = pk2bf(xa.z, xa.w);
        ap[2] = pk2bf(xb.x, xb.y); ap[3] = pk2bf(xb.z, xb.w);
        short8 af;
        __builtin_memcpy(&af, ap, 16);
        short8 bfg = *(const short8*)&WtO[(size_t)(c16 + l15) * 128 + ks * 32 + quad * 8];
        ha = __builtin_amdgcn_mfma_f32_16x16x32_bf16(af, bfg, ha, 0, 0, 0);
    }
    float part = 0.0f;
    {
        float b1o = out1_b[c16 + l15];
        float o2  = out2_w[c16 + l15];
        #pragma unroll
        for (int r = 0; r < 4; r++)
            part += ssp(ha[r] + b1o) * o2;
    }
    #pragma unroll
    for (int off = 32; off > 0; off >>= 1) part += __shfl_down(part, off);
    if (lane == 0) atomicAdd(&s_red, part);
    __syncthreads();
    if (tid == 0) out[blockIdx.x] = s_red + 32.0f * out2_b[0];

#undef KO_RFL
#undef TP_LOAD
#undef FMA_CHUNK
}

extern "C" void kernel_launch(void* const* d_in, const int* in_sizes, int n_in,
                              void* d_out, int out_size, void* d_ws, size_t ws_size,
                              hipStream_t stream)
{
    const int*   z      = (const int*)d_in[0];
    const float* pos    = (const float*)d_in[1];
    const float* emb    = (const float*)d_in[4];
    const float* mlp_w1 = (const float*)d_in[5];
    const float* mlp_b1 = (const float*)d_in[6];
    const float* mlp_w2 = (const float*)d_in[7];
    const float* mlp_b2 = (const float*)d_in[8];
    const float* cf1_w  = (const float*)d_in[9];
    const float* cf2_w  = (const float*)d_in[10];
    const float* cf2_b  = (const float*)d_in[11];
    const float* lin_w  = (const float*)d_in[12];
    const float* lin_b  = (const float*)d_in[13];
    const float* out1_w = (const float*)d_in[14];
    const float* out1_b = (const float*)d_in[15];
    const float* out2_w = (const float*)d_in[16];
    const float* out2_b = (const float*)d_in[17];

    // workspace carve-up (64B-aligned sections)
    char* p = (char*)d_ws;
    unsigned* koG = (unsigned*)p;                 p += (size_t)NMOL * 1024 * 4;          // 2.0 MB
    unsigned short* Tt = (unsigned short*)p;      p += (size_t)3 * (KTAB + 1) * 128 * 2; // 3.1 MB
    unsigned short* Wtall = (unsigned short*)p;   p += ((size_t)(N_WTALL + N_OUT1) * 2 + 63) & ~63ULL;
    unsigned short* Wmlp = (unsigned short*)p;    // (N_W1T + N_W2T) ushorts

    setup_a_kernel<<<NMOL + WB_BLOCKS, 256, 0, stream>>>(
        pos, koG, cf1_w, cf2_w, lin_w, out1_w, mlp_w1, mlp_w2,
        Wtall, Wmlp, Tt);

    setup_b_kernel<<<NTILE * 3, 256, 0, stream>>>(
        Wmlp, mlp_b1, mlp_b2, Tt);

    fused_schnet_kernel<<<NMOL, 512, 0, stream>>>(
        z, emb, koG, Tt, Wtall,
        cf2_b, lin_b, out1_b, out2_w, out2_b, (float*)d_out);
}